// Round 2
// baseline (1622.511 us; speedup 1.0000x reference)
//
#include <hip/hip_runtime.h>
#include <math.h>

#define NPTS 1024
#define CAND 224   // 7*32
#define KEFF 64
#define BATCH 2
#define NEGV -1e30f
#define PLANE (BATCH * NPTS * CAND)

// ABLATION ROUND 2: kgemm restored to x1 (measured: 49.2us total, L0=20.3us).
// All OTHER kernels repeated x17 (idempotent) to attribute the remaining ~211us.
#define KREP 17

// ================================================================ weight prep
__global__ __launch_bounds__(256) void kprep(const float* __restrict__ w0, const float* __restrict__ w1,
                                             const float* __restrict__ w2, const float* __restrict__ w3,
                                             const float* __restrict__ wl, float* __restrict__ wt) {
    __shared__ float tA[32][33];
    __shared__ float tB[32][33];
    int id = blockIdx.x;
    int t = threadIdx.x;
    int row = t >> 5, col = t & 31;
#pragma unroll 1
    for (int rep = 0; rep < KREP; ++rep) {
    const float* W = w0; int Cin = 256, Co = 128; float* WtA = wt; float* WtB = wt + 32768;
    int tc = 0, to = 0; bool isWL = false;
    if (id < 32)      { int r = id;      tc = r >> 2; to = r & 3; }
    else if (id < 48) { W = w1; Cin = 128; Co = 128; WtA = wt + 65536;  WtB = wt + 81920;  int r = id - 32; tc = r >> 2; to = r & 3; }
    else if (id < 56) { W = w2; Cin = 128; Co = 64;  WtA = wt + 98304;  WtB = wt + 106496; int r = id - 48; tc = r >> 1; to = r & 1; }
    else if (id < 60) { W = w3; Cin = 64;  Co = 64;  WtA = wt + 114688; WtB = wt + 118784; int r = id - 56; tc = r >> 1; to = r & 1; }
    else { isWL = true; int r = id - 60; tc = r / 12; to = r % 12; }
    if (!isWL) {
#pragma unroll
        for (int r = 0; r < 4; ++r) {
            int o = to * 32 + row + r * 8;
            int c = tc * 32 + col;
            float va = W[(size_t)o * 2 * Cin + c];
            tA[row + r * 8][col] = va;
            tB[row + r * 8][col] = W[(size_t)o * 2 * Cin + Cin + c] - va;
        }
        __syncthreads();
#pragma unroll
        for (int r = 0; r < 4; ++r) {
            int c = tc * 32 + row + r * 8;
            int o = to * 32 + col;
            WtA[(size_t)c * Co + o] = tA[col][row + r * 8];
            WtB[(size_t)c * Co + o] = tB[col][row + r * 8];
        }
    } else {
        float* wlT = wt + 122880;
#pragma unroll
        for (int r = 0; r < 4; ++r) {
            int o = to * 32 + row + r * 8;
            int c = tc * 32 + col;
            tA[row + r * 8][col] = wl[(size_t)o * 384 + c];
        }
        __syncthreads();
#pragma unroll
        for (int r = 0; r < 4; ++r) {
            int c = tc * 32 + row + r * 8;
            int o = to * 32 + col;
            wlT[(size_t)c * 384 + o] = tA[col][row + r * 8];
        }
    }
    __syncthreads();   // end-of-rep: LDS reuse
    }
}

// ================================================================ GEMM (A/Bv/sq) + banded gram partials
struct GP {
    const float* xin; int bstride; int Cin; int Co; int nch; int applyBN;
    const float* WtA; const float* WtB;
    const float* partPrev; const float* gPrev; const float* bePrev;
    float* A; float* Bv; float* sq; float* Dp;
};

__global__ __launch_bounds__(256) void kgemm(GP p) {
    __shared__ float smem[7168];      // roleA: Xs[1024], Wta@1024[2176], Wtb@3200[2176]; roleB: Xc[32][224]
    __shared__ float shsc[128];
    __shared__ float shsh[128];
    int t = threadIdx.x;
    if (p.applyBN && t < p.Cin) {
        const float* pp = p.partPrev;
        float s  = pp[t * 2]     + pp[(p.Cin + t) * 2];
        float s2 = pp[t * 2 + 1] + pp[(p.Cin + t) * 2 + 1];
        const float invc = 1.f / 131072.f;
        float mu = s * invc;
        float var = s2 * invc - mu * mu;
        float rs = rsqrtf(var + 1e-5f);
        float sc = p.gPrev[t] * rs;
        shsc[t] = sc;
        shsh[t] = p.bePrev[t] - mu * sc;
    }
    __syncthreads();
    int nOT = p.Co >> 6;
    int nABx = 32 * nOT * BATCH;
    if ((int)blockIdx.x < nABx) {
        // ---------------- role A: 32n x 64o tile; thread = 4o x 2n
        int id = blockIdx.x;
        int nt = id & 31; int rest = id >> 5;
        int ot = rest % nOT; int b = rest / nOT;
        int tn2 = (t & 15) * 2, to4 = (t >> 4) * 4;
        int n0 = nt * 32, o0 = ot * 64;
        const float* xb = p.xin + (size_t)b * p.bstride + n0;
        float* Xs = smem; float* Wta = smem + 1024; float* Wtb = smem + 3200;
        float2 a2[4], b2[4], s2v;
#pragma unroll
        for (int i = 0; i < 4; ++i) { a2[i] = make_float2(0.f,0.f); b2[i] = make_float2(0.f,0.f); }
        s2v = make_float2(0.f,0.f);
        int xcc0 = t >> 5, xnn = t & 31;   // k<4: cc = xcc0 + k*8
        int wcc0 = t >> 6, woo = t & 63;   // k<8: cc = wcc0 + k*4
        for (int c0 = 0; c0 < p.Cin; c0 += 32) {
            float rx[4], ra[8], rb[8];
#pragma unroll
            for (int k = 0; k < 4; ++k)
                rx[k] = xb[(size_t)(c0 + xcc0 + k * 8) * NPTS + xnn];
#pragma unroll
            for (int k = 0; k < 8; ++k) {
                ra[k] = p.WtA[(size_t)(c0 + wcc0 + k * 4) * p.Co + o0 + woo];
                rb[k] = p.WtB[(size_t)(c0 + wcc0 + k * 4) * p.Co + o0 + woo];
            }
            if (p.applyBN) {
#pragma unroll
                for (int k = 0; k < 4; ++k) {
                    int cc = xcc0 + k * 8;
                    float y = fmaf(rx[k], shsc[c0 + cc], shsh[c0 + cc]);
                    rx[k] = y >= 0.f ? y : 0.2f * y;
                }
            }
            __syncthreads();   // prev-tile compute done before overwrite
#pragma unroll
            for (int k = 0; k < 4; ++k)
                Xs[(xcc0 + k * 8) * 32 + xnn] = rx[k];
#pragma unroll
            for (int k = 0; k < 8; ++k) {
                Wta[(wcc0 + k * 4) * 68 + woo] = ra[k];
                Wtb[(wcc0 + k * 4) * 68 + woo] = rb[k];
            }
            __syncthreads();
#pragma unroll 8
            for (int cc = 0; cc < 32; ++cc) {
                float2 xv = *(const float2*)&Xs[cc * 32 + tn2];
                float4 wa = *(const float4*)&Wta[cc * 68 + to4];
                float4 wb = *(const float4*)&Wtb[cc * 68 + to4];
                s2v.x = fmaf(xv.x, xv.x, s2v.x);
                s2v.y = fmaf(xv.y, xv.y, s2v.y);
                float wav[4] = {wa.x, wa.y, wa.z, wa.w};
                float wbv[4] = {wb.x, wb.y, wb.z, wb.w};
#pragma unroll
                for (int i = 0; i < 4; ++i) {
                    a2[i].x = fmaf(wav[i], xv.x, a2[i].x);
                    a2[i].y = fmaf(wav[i], xv.y, a2[i].y);
                    b2[i].x = fmaf(wbv[i], xv.x, b2[i].x);
                    b2[i].y = fmaf(wbv[i], xv.y, b2[i].y);
                }
            }
        }
        int n = n0 + tn2;
        if (ot == 0 && to4 == 0)
            *(float2*)&p.sq[b * NPTS + n] = s2v;
#pragma unroll
        for (int i = 0; i < 4; ++i) {
            int o = o0 + to4 + i;
            size_t off = ((size_t)(b * p.Co + o)) * NPTS + n;
            *(float2*)&p.A[off] = a2[i];
            *(float2*)&p.Bv[off] = b2[i];
        }
    } else {
        // ---------------- role B: one 32-channel gram partial per block
        int id2 = blockIdx.x - nABx;
        int chunk = id2 % p.nch; int rest = id2 / p.nch;
        int i = rest & 31; int b = rest >> 5;
        int c0 = chunk * 32;
        const float* xb = p.xin + (size_t)b * p.bstride;
        float* Xc = smem;
        int q = t >> 3;
        int wg = t & 7;
        float r[28];
        int rcc[28], rw[28];
#pragma unroll
        for (int k = 0; k < 28; ++k) {
            int e = t + k * 256;
            int cc = e / CAND;
            int w  = e - cc * CAND;
            rcc[k] = cc; rw[k] = w;
            int wb = i - 3 + (w >> 5);
            wb = wb < 0 ? 0 : (wb > 31 ? 31 : wb);
            r[k] = xb[(size_t)(c0 + cc) * NPTS + wb * 32 + (w & 31)];
        }
        if (p.applyBN) {
#pragma unroll
            for (int k = 0; k < 28; ++k) {
                float y = fmaf(r[k], shsc[c0 + rcc[k]], shsh[c0 + rcc[k]]);
                r[k] = y >= 0.f ? y : 0.2f * y;
            }
        }
#pragma unroll
        for (int k = 0; k < 28; ++k)
            Xc[rcc[k] * CAND + rw[k]] = r[k];
        __syncthreads();
        float acc[28];
#pragma unroll
        for (int j = 0; j < 28; ++j) acc[j] = 0.f;
        for (int cc = 0; cc < 32; ++cc) {
            float qv = Xc[cc * CAND + 96 + q];
            const float4* row = (const float4*)&Xc[cc * CAND + wg * 28];
#pragma unroll
            for (int j4 = 0; j4 < 7; ++j4) {
                float4 v = row[j4];
                acc[j4 * 4 + 0] = fmaf(qv, v.x, acc[j4 * 4 + 0]);
                acc[j4 * 4 + 1] = fmaf(qv, v.y, acc[j4 * 4 + 1]);
                acc[j4 * 4 + 2] = fmaf(qv, v.z, acc[j4 * 4 + 2]);
                acc[j4 * 4 + 3] = fmaf(qv, v.w, acc[j4 * 4 + 3]);
            }
        }
        int n = i * 32 + q;
        size_t base = (((size_t)chunk * BATCH + b) * NPTS + n) * CAND + wg * 28;
        float4* outp = (float4*)&p.Dp[base];
#pragma unroll
        for (int j4 = 0; j4 < 7; ++j4)
            outp[j4] = make_float4(acc[j4 * 4], acc[j4 * 4 + 1], acc[j4 * 4 + 2], acc[j4 * 4 + 3]);
    }
}

// ================================================================ top-64 rank selection (64-bit keys); idx k-major
template<int NCH>
__global__ __launch_bounds__(256) void kselect(const float* __restrict__ Dp,
                                               const float* __restrict__ sq,
                                               int* __restrict__ idxo) {
    __shared__ ulonglong2 Dsh2[4][112];
    unsigned long long* Dsh = (unsigned long long*)Dsh2;
    int t = threadIdx.x;
    int wv = t >> 6, l = t & 63;
    int b = blockIdx.y;
    int n = blockIdx.x * 4 + wv;
    int i = n >> 5;
#pragma unroll 1
    for (int rep = 0; rep < KREP; ++rep) {
    float sqn = sq[b * NPTS + n];
    float pr[4][NCH];
    float sqw[4];
#pragma unroll
    for (int j = 0; j < 4; ++j) {
        int w = l + 64 * j;
        if (w < CAND) {
            size_t off = ((size_t)b * NPTS + n) * CAND + w;
#pragma unroll
            for (int ch = 0; ch < NCH; ++ch)
                pr[j][ch] = Dp[off + (size_t)ch * PLANE];
            int wb = i - 3 + (w >> 5);
            int wbc = wb < 0 ? 0 : (wb > 31 ? 31 : wb);
            sqw[j] = sq[b * NPTS + wbc * 32 + (w & 31)];
        }
    }
    unsigned long long kj[4];
#pragma unroll
    for (int j = 0; j < 4; ++j) {
        int w = l + 64 * j;
        if (w < CAND) {
            float s = 0.f;
#pragma unroll
            for (int ch = 0; ch < NCH; ++ch) s += pr[j][ch];
            int wb = i - 3 + (w >> 5);
            bool valid = (wb >= 0) && (wb < 32);
            float d = 2.f * s - sqn - sqw[j];
            d = valid ? d : NEGV;
            unsigned u = __float_as_uint(d);
            u ^= ((unsigned)((int)u >> 31)) | 0x80000000u;
            unsigned long long key = ((unsigned long long)u << 8) | (unsigned long long)(255 - w);
            kj[j] = key;
            Dsh[wv * 224 + w] = key;
        } else {
            kj[j] = 0ull;
        }
    }
    __syncthreads();
    int cnt[4] = {0, 0, 0, 0};
    const ulonglong2* row = Dsh2[wv];
#pragma unroll 2
    for (int w2 = 0; w2 < 112; w2 += 4) {
        ulonglong2 k0 = row[w2], k1 = row[w2 + 1], k2 = row[w2 + 2], k3 = row[w2 + 3];
#pragma unroll
        for (int j = 0; j < 4; ++j) {
            unsigned long long kk = kj[j];
            cnt[j] += (int)(k0.x > kk) + (int)(k0.y > kk) + (int)(k1.x > kk) + (int)(k1.y > kk)
                    + (int)(k2.x > kk) + (int)(k2.y > kk) + (int)(k3.x > kk) + (int)(k3.y > kk);
        }
    }
#pragma unroll
    for (int j = 0; j < 4; ++j) {
        int w = l + 64 * j;
        if (w < CAND && cnt[j] < KEFF)
            idxo[((size_t)b * KEFF + cnt[j]) * NPTS + n] = (i - 3) * 32 + w;   // k-major
    }
    __syncthreads();   // end-of-rep: Dsh reuse
    }
}

// ================================================================ gather + max/S1/S2 (idx k-major, coalesced)
__global__ __launch_bounds__(256) void kagg(const float* __restrict__ A, const float* __restrict__ Bv,
                                            const int* __restrict__ idx, int Co,
                                            float* __restrict__ xconM, int chOut,
                                            float* __restrict__ part) {
    __shared__ float Ash[NPTS];
    __shared__ float red[256];
    int o = blockIdx.x, b = blockIdx.y, t = threadIdx.x;
    size_t rowoff = ((size_t)(b * Co + o)) * NPTS;
#pragma unroll 1
    for (int rep = 0; rep < KREP; ++rep) {
    {
        float rA[4];
#pragma unroll
        for (int r = 0; r < 4; ++r) rA[r] = A[rowoff + r * 256 + t];
#pragma unroll
        for (int r = 0; r < 4; ++r) Ash[r * 256 + t] = rA[r];
    }
    __syncthreads();
    float sum = 0.f, sumsq = 0.f;
    for (int r = 0; r < 4; ++r) {
        int n = r * 256 + t;
        const int* ip = idx + (size_t)b * KEFF * NPTS + n;
        float s1 = 0.f, s2 = 0.f, mx = -3.4e38f;
#pragma unroll
        for (int kb = 0; kb < 4; ++kb) {
            int iv[16];
#pragma unroll
            for (int m = 0; m < 16; ++m)
                iv[m] = ip[(size_t)(kb * 16 + m) * NPTS];
            float av[16];
#pragma unroll
            for (int m = 0; m < 16; ++m) av[m] = Ash[iv[m]];
#pragma unroll
            for (int m = 0; m < 16; m += 4) {
                s1 += av[m] + av[m+1] + av[m+2] + av[m+3];
                s2 += av[m]*av[m] + av[m+1]*av[m+1] + av[m+2]*av[m+2] + av[m+3]*av[m+3];
                mx = fmaxf(mx, fmaxf(fmaxf(av[m], av[m+1]), fmaxf(av[m+2], av[m+3])));
            }
        }
        float bv = Bv[rowoff + n];
        xconM[((size_t)b * 384 + chOut + o) * NPTS + n] = mx + bv;
        sum   += s1 + 64.f * bv;
        sumsq += s2 + 2.f * bv * s1 + 64.f * bv * bv;
    }
    red[t] = sum; __syncthreads();
    for (int s = 128; s > 0; s >>= 1) { if (t < s) red[t] += red[t + s]; __syncthreads(); }
    if (t == 0) part[((size_t)(b * Co + o)) * 2 + 0] = red[0];
    __syncthreads();
    red[t] = sumsq; __syncthreads();
    for (int s = 128; s > 0; s >>= 1) { if (t < s) red[t] += red[t + s]; __syncthreads(); }
    if (t == 0) part[((size_t)(b * Co + o)) * 2 + 1] = red[0];
    __syncthreads();   // end-of-rep: Ash/red reuse
    }
}

// ================================================================ final GEMM with BN+leaky on load
struct FP {
    const float* part0; const float* part1; const float* part2; const float* part3;
    const float* g0; const float* g1; const float* g2; const float* g3;
    const float* be0; const float* be1; const float* be2; const float* be3;
};

__global__ __launch_bounds__(256) void kfinal(const float* __restrict__ xconM,
                                              const float* __restrict__ wlT, FP p,
                                              float* __restrict__ out) {
    __shared__ float Xs[2048];
    __shared__ float Wl[2176];
    __shared__ float shsc[384];
    __shared__ float shsh[384];
    int t = threadIdx.x;
#pragma unroll 1
    for (int rep = 0; rep < KREP; ++rep) {
    for (int ch = t; ch < 384; ch += 256) {
        const float* pl; const float* gl; const float* bl; int o, Col;
        if (ch < 128)      { pl = p.part0; gl = p.g0; bl = p.be0; o = ch;       Col = 128; }
        else if (ch < 256) { pl = p.part1; gl = p.g1; bl = p.be1; o = ch - 128; Col = 128; }
        else if (ch < 320) { pl = p.part2; gl = p.g2; bl = p.be2; o = ch - 256; Col = 64;  }
        else               { pl = p.part3; gl = p.g3; bl = p.be3; o = ch - 320; Col = 64;  }
        float s  = pl[o * 2]     + pl[(Col + o) * 2];
        float s2 = pl[o * 2 + 1] + pl[(Col + o) * 2 + 1];
        const float invc = 1.f / 131072.f;
        float mu = s * invc;
        float var = s2 * invc - mu * mu;
        float rs = rsqrtf(var + 1e-5f);
        float sc = gl[o] * rs;
        shsc[ch] = sc;
        shsh[ch] = bl[o] - mu * sc;
    }
    __syncthreads();
    int tn4 = (t & 15) * 4, to4 = (t >> 4) * 4;
    int n0 = blockIdx.x * 64, o0 = blockIdx.y * 64, b = blockIdx.z;
    int cc0 = t >> 6, nn0 = t & 63;
    float4 acc[4];
#pragma unroll
    for (int i = 0; i < 4; ++i) acc[i] = make_float4(0.f,0.f,0.f,0.f);
    for (int c0 = 0; c0 < 384; c0 += 32) {
        float rx[8], rw[8];
#pragma unroll
        for (int k = 0; k < 8; ++k) {
            int cc = cc0 + k * 4;
            rx[k] = xconM[((size_t)b * 384 + c0 + cc) * NPTS + n0 + nn0];
            rw[k] = wlT[(size_t)(c0 + cc) * 384 + o0 + nn0];
        }
#pragma unroll
        for (int k = 0; k < 8; ++k) {
            int cc = cc0 + k * 4;
            float y = fmaf(rx[k], shsc[c0 + cc], shsh[c0 + cc]);
            rx[k] = y >= 0.f ? y : 0.2f * y;
        }
        __syncthreads();
#pragma unroll
        for (int k = 0; k < 8; ++k) {
            int cc = cc0 + k * 4;
            Xs[cc * 64 + nn0] = rx[k];
            Wl[cc * 68 + nn0] = rw[k];
        }
        __syncthreads();
#pragma unroll 4
        for (int cc = 0; cc < 32; ++cc) {
            float4 xv = *(const float4*)&Xs[cc * 64 + tn4];
            float4 wv = *(const float4*)&Wl[cc * 68 + to4];
            float wvv[4] = {wv.x, wv.y, wv.z, wv.w};
#pragma unroll
            for (int i = 0; i < 4; ++i) {
                acc[i].x = fmaf(wvv[i], xv.x, acc[i].x);
                acc[i].y = fmaf(wvv[i], xv.y, acc[i].y);
                acc[i].z = fmaf(wvv[i], xv.z, acc[i].z);
                acc[i].w = fmaf(wvv[i], xv.w, acc[i].w);
            }
        }
    }
#pragma unroll
    for (int i = 0; i < 4; ++i)
        *(float4*)&out[((size_t)b * 384 + o0 + to4 + i) * NPTS + n0 + tn4] = acc[i];
    __syncthreads();   // end-of-rep: shsc/Xs reuse
    }
}

extern "C" void kernel_launch(void* const* d_in, const int* in_sizes, int n_in,
                              void* d_out, int out_size, void* d_ws, size_t ws_size,
                              hipStream_t stream) {
    const float* x  = (const float*)d_in[0];
    const float* w[4]  = {(const float*)d_in[1], (const float*)d_in[4], (const float*)d_in[7], (const float*)d_in[10]};
    const float* g[4]  = {(const float*)d_in[2], (const float*)d_in[5], (const float*)d_in[8], (const float*)d_in[11]};
    const float* be[4] = {(const float*)d_in[3], (const float*)d_in[6], (const float*)d_in[9], (const float*)d_in[12]};
    const float* wl = (const float*)d_in[13];

    float* ws    = (float*)d_ws;
    float* xconM = ws;                       // 786432
    float* A     = xconM + 786432;           // 262144
    float* Bv    = A + 262144;               // 262144
    float* sq    = Bv + 262144;              // 2048
    float* Dp    = sq + 2048;                // 8 planes * 458752 = 3670016
    float* part  = Dp + 3670016;             // 2048
    float* wt    = part + 2048;              // 270336
    int*   idx   = (int*)(wt + 270336);      // 131072 ints (k-major: [b][k][n])

    kprep<<<204, 256, 0, stream>>>(w[0], w[1], w[2], w[3], wl, wt);

    struct LC { const float* xin; int bstride; int Cin; int Co; int nch; int chOut;
                const float* wtA; const float* wtB; };
    LC L[4] = {
        { x,                  256 * 1024, 256, 128, 8, 0,   wt,          wt + 32768  },
        { xconM,              384 * 1024, 128, 128, 4, 128, wt + 65536,  wt + 81920  },
        { xconM + 128 * 1024, 384 * 1024, 128, 64,  4, 256, wt + 98304,  wt + 106496 },
        { xconM + 256 * 1024, 384 * 1024, 64,  64,  2, 320, wt + 114688, wt + 118784 },
    };

    for (int l = 0; l < 4; ++l) {
        GP gp;
        gp.xin = L[l].xin; gp.bstride = L[l].bstride; gp.Cin = L[l].Cin; gp.Co = L[l].Co;
        gp.nch = L[l].nch; gp.applyBN = (l > 0);
        gp.WtA = L[l].wtA; gp.WtB = L[l].wtB;
        gp.partPrev = (l > 0) ? part + (l - 1) * 512 : nullptr;
        gp.gPrev = (l > 0) ? g[l - 1] : nullptr;
        gp.bePrev = (l > 0) ? be[l - 1] : nullptr;
        gp.A = A; gp.Bv = Bv; gp.sq = sq; gp.Dp = Dp;
        int nAB = 32 * (L[l].Co >> 6) * BATCH;
        int nDist = L[l].nch * 32 * BATCH;
        kgemm<<<nAB + nDist, 256, 0, stream>>>(gp);
        if (L[l].nch == 8)      kselect<8><<<dim3(NPTS / 4, BATCH), 256, 0, stream>>>(Dp, sq, idx);
        else if (L[l].nch == 4) kselect<4><<<dim3(NPTS / 4, BATCH), 256, 0, stream>>>(Dp, sq, idx);
        else                    kselect<2><<<dim3(NPTS / 4, BATCH), 256, 0, stream>>>(Dp, sq, idx);
        kagg<<<dim3(L[l].Co, BATCH), 256, 0, stream>>>(A, Bv, idx, L[l].Co, xconM, L[l].chOut, part + l * 512);
    }

    FP fp;
    fp.part0 = part; fp.part1 = part + 512; fp.part2 = part + 1024; fp.part3 = part + 1536;
    fp.g0 = g[0]; fp.g1 = g[1]; fp.g2 = g[2]; fp.g3 = g[3];
    fp.be0 = be[0]; fp.be1 = be[1]; fp.be2 = be[2]; fp.be3 = be[3];
    kfinal<<<dim3(16, 6, BATCH), 256, 0, stream>>>(xconM, wt + 122880, fp, (float*)d_out);
}

// Round 4
// 1264.097 us; speedup vs baseline: 1.2835x; 1.2835x over previous
//
#include <hip/hip_runtime.h>
#include <math.h>

#define NPTS 1024
#define CAND 224   // 7*32
#define KEFF 64
#define BATCH 2
#define NEGV -1e30f
#define PLANE (BATCH * NPTS * CAND)
#define NBLK 512

// R4 = R3 fusion with the part-buffer overlap FIXED (per-layer stride 512 -> 1024).
// R3 failure: layer l wrote 4*2*Co partial floats (1024 for Co=128) into a 512-float
// region; layers 1/2 clobbered layers 0/1's partials before kfinal's BN re-read them.

// ================================================================ weight prep (+ barrier init)
__global__ __launch_bounds__(256) void kprep(const float* __restrict__ w0, const float* __restrict__ w1,
                                             const float* __restrict__ w2, const float* __restrict__ w3,
                                             const float* __restrict__ wl, float* __restrict__ wt,
                                             unsigned* __restrict__ bar) {
    __shared__ float tA[32][33];
    __shared__ float tB[32][33];
    int id = blockIdx.x;
    int t = threadIdx.x;
    if (id == 0 && t == 0) bar[0] = 0u;          // reset grid-barrier counter each launch
    int row = t >> 5, col = t & 31;
    const float* W = w0; int Cin = 256, Co = 128; float* WtA = wt; float* WtB = wt + 32768;
    int tc = 0, to = 0; bool isWL = false;
    if (id < 32)      { int r = id;      tc = r >> 2; to = r & 3; }
    else if (id < 48) { W = w1; Cin = 128; Co = 128; WtA = wt + 65536;  WtB = wt + 81920;  int r = id - 32; tc = r >> 2; to = r & 3; }
    else if (id < 56) { W = w2; Cin = 128; Co = 64;  WtA = wt + 98304;  WtB = wt + 106496; int r = id - 48; tc = r >> 1; to = r & 1; }
    else if (id < 60) { W = w3; Cin = 64;  Co = 64;  WtA = wt + 114688; WtB = wt + 118784; int r = id - 56; tc = r >> 1; to = r & 1; }
    else { isWL = true; int r = id - 60; tc = r / 12; to = r % 12; }
    if (!isWL) {
#pragma unroll
        for (int r = 0; r < 4; ++r) {
            int o = to * 32 + row + r * 8;
            int c = tc * 32 + col;
            float va = W[(size_t)o * 2 * Cin + c];
            tA[row + r * 8][col] = va;
            tB[row + r * 8][col] = W[(size_t)o * 2 * Cin + Cin + c] - va;
        }
        __syncthreads();
#pragma unroll
        for (int r = 0; r < 4; ++r) {
            int c = tc * 32 + row + r * 8;
            int o = to * 32 + col;
            WtA[(size_t)c * Co + o] = tA[col][row + r * 8];
            WtB[(size_t)c * Co + o] = tB[col][row + r * 8];
        }
    } else {
        float* wlT = wt + 122880;
#pragma unroll
        for (int r = 0; r < 4; ++r) {
            int o = to * 32 + row + r * 8;
            int c = tc * 32 + col;
            tA[row + r * 8][col] = wl[(size_t)o * 384 + c];
        }
        __syncthreads();
#pragma unroll
        for (int r = 0; r < 4; ++r) {
            int c = tc * 32 + row + r * 8;
            int o = to * 32 + col;
            wlT[(size_t)c * 384 + o] = tA[col][row + r * 8];
        }
    }
}

// ================================================================ grid barrier (monotone counter)
__device__ __forceinline__ void gbar(unsigned* cnt) {
    __syncthreads();
    if (threadIdx.x == 0) {
        __threadfence();   // release: make this block's stores device-visible
        unsigned my = __hip_atomic_fetch_add(cnt, 1u, __ATOMIC_ACQ_REL, __HIP_MEMORY_SCOPE_AGENT);
        unsigned tgt = (my / NBLK + 1u) * NBLK;
        while (__hip_atomic_load(cnt, __ATOMIC_ACQUIRE, __HIP_MEMORY_SCOPE_AGENT) < tgt)
            __builtin_amdgcn_s_sleep(1);
        __threadfence();   // acquire side
    }
    __syncthreads();
}

// ================================================================ select stage (per layer)
template<int NCH>
__device__ __forceinline__ void sel_stage(const float* __restrict__ Dp, const float* __restrict__ sq,
                                          int* __restrict__ idxo, float* smem, int bid, int t) {
    unsigned long long* Dsh = (unsigned long long*)smem;
    int wv = t >> 6, ln = t & 63;
#pragma unroll 1
    for (int job = bid; job < 512; job += NBLK) {
        int b = job >> 8;
        int n = (job & 255) * 4 + wv;
        int i = n >> 5;
        float sqn = sq[b * NPTS + n];
        float pr[4][NCH];
        float sqw[4];
#pragma unroll
        for (int j = 0; j < 4; ++j) {
            int w = ln + 64 * j;
            if (w < CAND) {
                size_t off = ((size_t)b * NPTS + n) * CAND + w;
#pragma unroll
                for (int ch = 0; ch < NCH; ++ch)
                    pr[j][ch] = Dp[off + (size_t)ch * PLANE];
                int wb = i - 3 + (w >> 5);
                int wbc = wb < 0 ? 0 : (wb > 31 ? 31 : wb);
                sqw[j] = sq[b * NPTS + wbc * 32 + (w & 31)];
            }
        }
        unsigned long long kj[4];
#pragma unroll
        for (int j = 0; j < 4; ++j) {
            int w = ln + 64 * j;
            if (w < CAND) {
                float s = 0.f;
#pragma unroll
                for (int ch = 0; ch < NCH; ++ch) s += pr[j][ch];
                int wb = i - 3 + (w >> 5);
                bool valid = (wb >= 0) && (wb < 32);
                float d = 2.f * s - sqn - sqw[j];
                d = valid ? d : NEGV;
                unsigned u = __float_as_uint(d);
                u ^= ((unsigned)((int)u >> 31)) | 0x80000000u;
                unsigned long long key = ((unsigned long long)u << 8) | (unsigned long long)(255 - w);
                kj[j] = key;
                Dsh[wv * 224 + w] = key;
            } else {
                kj[j] = 0ull;
            }
        }
        __syncthreads();
        int cnt[4] = {0, 0, 0, 0};
        const ulonglong2* row = (const ulonglong2*)(Dsh + wv * 224);
#pragma unroll 2
        for (int w2 = 0; w2 < 112; w2 += 4) {
            ulonglong2 k0 = row[w2], k1 = row[w2 + 1], k2 = row[w2 + 2], k3 = row[w2 + 3];
#pragma unroll
            for (int j = 0; j < 4; ++j) {
                unsigned long long kk = kj[j];
                cnt[j] += (int)(k0.x > kk) + (int)(k0.y > kk) + (int)(k1.x > kk) + (int)(k1.y > kk)
                        + (int)(k2.x > kk) + (int)(k2.y > kk) + (int)(k3.x > kk) + (int)(k3.y > kk);
            }
        }
#pragma unroll
        for (int j = 0; j < 4; ++j) {
            int w = ln + 64 * j;
            if (w < CAND && cnt[j] < KEFF)
                idxo[((size_t)b * KEFF + cnt[j]) * NPTS + n] = (i - 3) * 32 + w;   // k-major
        }
        __syncthreads();
    }
}

// ================================================================ the fused persistent kernel
struct MP {
    const float* x;
    const float* g0; const float* g1; const float* g2; const float* g3;
    const float* be0; const float* be1; const float* be2; const float* be3;
    float* xconM; float* A; float* Bv; float* sq; float* Dp; float* part; float* wt;
    int* idx; unsigned* bar; float* out;
};

__global__ __launch_bounds__(256, 3) void kmega(MP P) {
    __shared__ __align__(16) float smem[7168];
    __shared__ float shsc[384];
    __shared__ float shsh[384];
    const int t = threadIdx.x;
    const int bid = blockIdx.x;

#pragma unroll 1
    for (int l = 0; l < 4; ++l) {
        const int Cin   = (l == 0) ? 256 : (l == 3) ? 64 : 128;
        const int Co    = (l < 2) ? 128 : 64;
        const int nch   = (l == 0) ? 8 : (l == 3) ? 2 : 4;
        const int nchLg = (l == 0) ? 3 : (l == 3) ? 1 : 2;
        const int chOut = (l == 0) ? 0 : (l == 1) ? 128 : (l == 2) ? 256 : 320;
        const float* xin = (l == 0) ? P.x : P.xconM + (size_t)(l - 1) * 131072;
        const int bstride = (l == 0) ? 262144 : 393216;
        const float* WtA = P.wt + ((l == 0) ? 0 : (l == 1) ? 65536 : (l == 2) ? 98304 : 114688);
        const float* WtB = P.wt + ((l == 0) ? 32768 : (l == 1) ? 81920 : (l == 2) ? 106496 : 118784);

        // BN scale/shift for this layer's input (prev layer's 4 partials per channel)
        if (l > 0 && t < Cin) {
            const float* pp = P.part + (size_t)(l - 1) * 1024;
            const float* gPr = (l == 1) ? P.g0  : (l == 2) ? P.g1  : P.g2;
            const float* bPr = (l == 1) ? P.be0 : (l == 2) ? P.be1 : P.be2;
            float s  = pp[4 * t]     + pp[4 * t + 2]     + pp[4 * (Cin + t)]     + pp[4 * (Cin + t) + 2];
            float s2 = pp[4 * t + 1] + pp[4 * t + 3]     + pp[4 * (Cin + t) + 1] + pp[4 * (Cin + t) + 3];
            const float invc = 1.f / 131072.f;
            float mu = s * invc;
            float var = s2 * invc - mu * mu;
            float rs = rsqrtf(var + 1e-5f);
            float sc = gPr[t] * rs;
            shsc[t] = sc;
            shsh[t] = bPr[t] - mu * sc;
        }
        __syncthreads();

        // ---------------- gemm stage (role A: A/Bv/sq tiles; role B: gram partials)
        const int nOT = Co >> 6;
        const int notLg = nOT - 1;          // 2->1, 1->0
        const int nABx = 32 * nOT * BATCH;
        const int nJobs = nABx + nch * 32 * BATCH;
#pragma unroll 1
        for (int job = bid; job < nJobs; job += NBLK) {
            if (job < nABx) {
                int nt = job & 31; int rest = job >> 5;
                int ot = rest & (nOT - 1); int b = rest >> notLg;
                int tn2 = (t & 15) * 2, to4 = (t >> 4) * 4;
                int n0 = nt * 32, o0 = ot * 64;
                const float* xb = xin + (size_t)b * bstride + n0;
                float* Xs = smem; float* Wta = smem + 1024; float* Wtb = smem + 3200;
                float2 a2[4], b2[4], s2v;
#pragma unroll
                for (int q = 0; q < 4; ++q) { a2[q] = make_float2(0.f, 0.f); b2[q] = make_float2(0.f, 0.f); }
                s2v = make_float2(0.f, 0.f);
                int xcc0 = t >> 5, xnn = t & 31;
                int wcc0 = t >> 6, woo = t & 63;
                for (int c0 = 0; c0 < Cin; c0 += 32) {
                    float rx[4], ra[8], rb[8];
#pragma unroll
                    for (int k = 0; k < 4; ++k)
                        rx[k] = xb[(size_t)(c0 + xcc0 + k * 8) * NPTS + xnn];
#pragma unroll
                    for (int k = 0; k < 8; ++k) {
                        ra[k] = WtA[(size_t)(c0 + wcc0 + k * 4) * Co + o0 + woo];
                        rb[k] = WtB[(size_t)(c0 + wcc0 + k * 4) * Co + o0 + woo];
                    }
                    if (l > 0) {
#pragma unroll
                        for (int k = 0; k < 4; ++k) {
                            int cc = xcc0 + k * 8;
                            float y = fmaf(rx[k], shsc[c0 + cc], shsh[c0 + cc]);
                            rx[k] = y >= 0.f ? y : 0.2f * y;
                        }
                    }
                    __syncthreads();
#pragma unroll
                    for (int k = 0; k < 4; ++k)
                        Xs[(xcc0 + k * 8) * 32 + xnn] = rx[k];
#pragma unroll
                    for (int k = 0; k < 8; ++k) {
                        Wta[(wcc0 + k * 4) * 68 + woo] = ra[k];
                        Wtb[(wcc0 + k * 4) * 68 + woo] = rb[k];
                    }
                    __syncthreads();
#pragma unroll 8
                    for (int cc = 0; cc < 32; ++cc) {
                        float2 xv = *(const float2*)&Xs[cc * 32 + tn2];
                        float4 wa = *(const float4*)&Wta[cc * 68 + to4];
                        float4 wb = *(const float4*)&Wtb[cc * 68 + to4];
                        s2v.x = fmaf(xv.x, xv.x, s2v.x);
                        s2v.y = fmaf(xv.y, xv.y, s2v.y);
                        float wav[4] = {wa.x, wa.y, wa.z, wa.w};
                        float wbv[4] = {wb.x, wb.y, wb.z, wb.w};
#pragma unroll
                        for (int q = 0; q < 4; ++q) {
                            a2[q].x = fmaf(wav[q], xv.x, a2[q].x);
                            a2[q].y = fmaf(wav[q], xv.y, a2[q].y);
                            b2[q].x = fmaf(wbv[q], xv.x, b2[q].x);
                            b2[q].y = fmaf(wbv[q], xv.y, b2[q].y);
                        }
                    }
                }
                int n = n0 + tn2;
                if (ot == 0 && to4 == 0)
                    *(float2*)&P.sq[b * NPTS + n] = s2v;
#pragma unroll
                for (int q = 0; q < 4; ++q) {
                    int o = o0 + to4 + q;
                    size_t off = ((size_t)(b * Co + o)) * NPTS + n;
                    *(float2*)&P.A[off] = a2[q];
                    *(float2*)&P.Bv[off] = b2[q];
                }
            } else {
                int id2 = job - nABx;
                int chunk = id2 & (nch - 1); int rest = id2 >> nchLg;
                int i = rest & 31; int b = rest >> 5;
                int c0 = chunk * 32;
                const float* xb = xin + (size_t)b * bstride;
                float* Xc = smem;
                int q = t >> 3;
                int wg = t & 7;
                float r[28];
                int rcc[28], rw[28];
#pragma unroll
                for (int k = 0; k < 28; ++k) {
                    int e = t + k * 256;
                    int cc = e / CAND;
                    int w  = e - cc * CAND;
                    rcc[k] = cc; rw[k] = w;
                    int wb = i - 3 + (w >> 5);
                    wb = wb < 0 ? 0 : (wb > 31 ? 31 : wb);
                    r[k] = xb[(size_t)(c0 + cc) * NPTS + wb * 32 + (w & 31)];
                }
                if (l > 0) {
#pragma unroll
                    for (int k = 0; k < 28; ++k) {
                        float y = fmaf(r[k], shsc[c0 + rcc[k]], shsh[c0 + rcc[k]]);
                        r[k] = y >= 0.f ? y : 0.2f * y;
                    }
                }
#pragma unroll
                for (int k = 0; k < 28; ++k)
                    Xc[rcc[k] * CAND + rw[k]] = r[k];
                __syncthreads();
                float acc[28];
#pragma unroll
                for (int j = 0; j < 28; ++j) acc[j] = 0.f;
                for (int cc = 0; cc < 32; ++cc) {
                    float qv = Xc[cc * CAND + 96 + q];
                    const float4* rowp = (const float4*)&Xc[cc * CAND + wg * 28];
#pragma unroll
                    for (int j4 = 0; j4 < 7; ++j4) {
                        float4 v = rowp[j4];
                        acc[j4 * 4 + 0] = fmaf(qv, v.x, acc[j4 * 4 + 0]);
                        acc[j4 * 4 + 1] = fmaf(qv, v.y, acc[j4 * 4 + 1]);
                        acc[j4 * 4 + 2] = fmaf(qv, v.z, acc[j4 * 4 + 2]);
                        acc[j4 * 4 + 3] = fmaf(qv, v.w, acc[j4 * 4 + 3]);
                    }
                }
                int n = i * 32 + q;
                size_t base = (((size_t)chunk * BATCH + b) * NPTS + n) * CAND + wg * 28;
                float4* outp = (float4*)&P.Dp[base];
#pragma unroll
                for (int j4 = 0; j4 < 7; ++j4)
                    outp[j4] = make_float4(acc[j4 * 4], acc[j4 * 4 + 1], acc[j4 * 4 + 2], acc[j4 * 4 + 3]);
            }
            __syncthreads();   // job-end: LDS reuse safe
        }
        gbar(P.bar);

        // ---------------- select stage
        if (nch == 8)      sel_stage<8>(P.Dp, P.sq, P.idx, smem, bid, t);
        else if (nch == 4) sel_stage<4>(P.Dp, P.sq, P.idx, smem, bid, t);
        else               sel_stage<2>(P.Dp, P.sq, P.idx, smem, bid, t);
        gbar(P.bar);

        // ---------------- agg stage (n split into 2 halves -> Co*4 jobs)
        const int CoLg = (Co == 128) ? 7 : 6;
#pragma unroll 1
        for (int job = bid; job < Co * 4; job += NBLK) {
            int o = job & (Co - 1); int rest = job >> CoLg;
            int b = rest & 1; int h = rest >> 1;
            float* Ash = smem;
            float* red = smem + 1024;
            size_t rowoff = (size_t)(b * Co + o) * NPTS;
            {
                float rA[4];
#pragma unroll
                for (int r = 0; r < 4; ++r) rA[r] = P.A[rowoff + r * 256 + t];
#pragma unroll
                for (int r = 0; r < 4; ++r) Ash[r * 256 + t] = rA[r];
            }
            __syncthreads();
            float sum = 0.f, sumsq = 0.f;
#pragma unroll 1
            for (int r = 0; r < 2; ++r) {
                int n = h * 512 + r * 256 + t;
                const int* ip = P.idx + (size_t)b * KEFF * NPTS + n;
                float s1 = 0.f, s2 = 0.f, mx = -3.4e38f;
#pragma unroll
                for (int kb = 0; kb < 4; ++kb) {
                    int iv[16];
#pragma unroll
                    for (int m = 0; m < 16; ++m)
                        iv[m] = ip[(size_t)(kb * 16 + m) * NPTS];
                    float av[16];
#pragma unroll
                    for (int m = 0; m < 16; ++m) av[m] = Ash[iv[m]];
#pragma unroll
                    for (int m = 0; m < 16; m += 4) {
                        s1 += av[m] + av[m+1] + av[m+2] + av[m+3];
                        s2 += av[m]*av[m] + av[m+1]*av[m+1] + av[m+2]*av[m+2] + av[m+3]*av[m+3];
                        mx = fmaxf(mx, fmaxf(fmaxf(av[m], av[m+1]), fmaxf(av[m+2], av[m+3])));
                    }
                }
                float bv = P.Bv[rowoff + n];
                P.xconM[((size_t)b * 384 + chOut + o) * NPTS + n] = mx + bv;
                sum   += s1 + 64.f * bv;
                sumsq += s2 + 2.f * bv * s1 + 64.f * bv * bv;
            }
            red[t] = sum; __syncthreads();
            for (int s = 128; s > 0; s >>= 1) { if (t < s) red[t] += red[t + s]; __syncthreads(); }
            if (t == 0) P.part[(size_t)l * 1024 + ((b * Co + o) * 2 + h) * 2 + 0] = red[0];
            __syncthreads();
            red[t] = sumsq; __syncthreads();
            for (int s = 128; s > 0; s >>= 1) { if (t < s) red[t] += red[t + s]; __syncthreads(); }
            if (t == 0) P.part[(size_t)l * 1024 + ((b * Co + o) * 2 + h) * 2 + 1] = red[0];
            __syncthreads();
        }
        gbar(P.bar);
    }

    // ---------------- final GEMM (64o x 32n tiles -> 384 jobs)
    for (int ch = t; ch < 384; ch += 256) {
        const float* pl; const float* gl; const float* bl; int o, Col;
        if (ch < 128)      { pl = P.part;         gl = P.g0; bl = P.be0; o = ch;       Col = 128; }
        else if (ch < 256) { pl = P.part + 1024;  gl = P.g1; bl = P.be1; o = ch - 128; Col = 128; }
        else if (ch < 320) { pl = P.part + 2048;  gl = P.g2; bl = P.be2; o = ch - 256; Col = 64;  }
        else               { pl = P.part + 3072;  gl = P.g3; bl = P.be3; o = ch - 320; Col = 64;  }
        float s  = pl[4 * o]     + pl[4 * o + 2]     + pl[4 * (Col + o)]     + pl[4 * (Col + o) + 2];
        float s2 = pl[4 * o + 1] + pl[4 * o + 3]     + pl[4 * (Col + o) + 1] + pl[4 * (Col + o) + 3];
        const float invc = 1.f / 131072.f;
        float mu = s * invc;
        float var = s2 * invc - mu * mu;
        float rs = rsqrtf(var + 1e-5f);
        float sc = gl[o] * rs;
        shsc[ch] = sc;
        shsh[ch] = bl[o] - mu * sc;
    }
    __syncthreads();
    const float* wlT = P.wt + 122880;
#pragma unroll 1
    for (int job = bid; job < 384; job += NBLK) {
        int nt = job & 31; int rest = job >> 5;
        int ot = rest % 6; int b = rest / 6;
        int n0 = nt * 32, o0 = ot * 64;
        int tn2 = (t & 15) * 2, to4 = (t >> 4) * 4;
        int nn = t & 31, cx0 = t >> 5;
        int woo = t & 63, cw0 = t >> 6;
        float* Xs = smem;
        float* Wl = smem + 1024;
        float2 acc2[4];
#pragma unroll
        for (int i = 0; i < 4; ++i) acc2[i] = make_float2(0.f, 0.f);
        for (int c0 = 0; c0 < 384; c0 += 32) {
            float rx[4], rw[8];
#pragma unroll
            for (int k = 0; k < 4; ++k)
                rx[k] = P.xconM[((size_t)b * 384 + c0 + cx0 + k * 8) * NPTS + n0 + nn];
#pragma unroll
            for (int k = 0; k < 8; ++k)
                rw[k] = wlT[(size_t)(c0 + cw0 + k * 4) * 384 + o0 + woo];
#pragma unroll
            for (int k = 0; k < 4; ++k) {
                int cc = c0 + cx0 + k * 8;
                float y = fmaf(rx[k], shsc[cc], shsh[cc]);
                rx[k] = y >= 0.f ? y : 0.2f * y;
            }
            __syncthreads();
#pragma unroll
            for (int k = 0; k < 4; ++k)
                Xs[(cx0 + k * 8) * 32 + nn] = rx[k];
#pragma unroll
            for (int k = 0; k < 8; ++k)
                Wl[(cw0 + k * 4) * 68 + woo] = rw[k];
            __syncthreads();
#pragma unroll 8
            for (int cc = 0; cc < 32; ++cc) {
                float2 xv = *(const float2*)&Xs[cc * 32 + tn2];
                float4 wv = *(const float4*)&Wl[cc * 68 + to4];
                float wvv[4] = {wv.x, wv.y, wv.z, wv.w};
#pragma unroll
                for (int i = 0; i < 4; ++i) {
                    acc2[i].x = fmaf(wvv[i], xv.x, acc2[i].x);
                    acc2[i].y = fmaf(wvv[i], xv.y, acc2[i].y);
                }
            }
        }
#pragma unroll
        for (int i = 0; i < 4; ++i)
            *(float2*)&P.out[((size_t)b * 384 + o0 + to4 + i) * NPTS + n0 + tn2] = acc2[i];
        __syncthreads();
    }
}

extern "C" void kernel_launch(void* const* d_in, const int* in_sizes, int n_in,
                              void* d_out, int out_size, void* d_ws, size_t ws_size,
                              hipStream_t stream) {
    const float* x  = (const float*)d_in[0];
    const float* w[4]  = {(const float*)d_in[1], (const float*)d_in[4], (const float*)d_in[7], (const float*)d_in[10]};
    const float* g[4]  = {(const float*)d_in[2], (const float*)d_in[5], (const float*)d_in[8], (const float*)d_in[11]};
    const float* be[4] = {(const float*)d_in[3], (const float*)d_in[6], (const float*)d_in[9], (const float*)d_in[12]};
    const float* wl = (const float*)d_in[13];

    float* ws    = (float*)d_ws;
    float* xconM = ws;                       // 786432
    float* A     = xconM + 786432;           // 262144
    float* Bv    = A + 262144;               // 262144
    float* sq    = Bv + 262144;              // 2048
    float* Dp    = sq + 2048;                // 8 planes * 458752 = 3670016
    float* part  = Dp + 3670016;             // 4096 (4 layers x 1024: [b][o][h][{s1,s2}])
    float* wt    = part + 4096;              // 270336
    int*   idx   = (int*)(wt + 270336);      // 131072 ints (k-major: [b][k][n])
    unsigned* bar = (unsigned*)(idx + 131072);

    kprep<<<204, 256, 0, stream>>>(w[0], w[1], w[2], w[3], wl, wt, bar);

    MP mp;
    mp.x = x;
    mp.g0 = g[0]; mp.g1 = g[1]; mp.g2 = g[2]; mp.g3 = g[3];
    mp.be0 = be[0]; mp.be1 = be[1]; mp.be2 = be[2]; mp.be3 = be[3];
    mp.xconM = xconM; mp.A = A; mp.Bv = Bv; mp.sq = sq; mp.Dp = Dp;
    mp.part = part; mp.wt = wt; mp.idx = idx; mp.bar = bar;
    mp.out = (float*)d_out;
    kmega<<<NBLK, 256, 0, stream>>>(mp);
}

// Round 5
// 467.735 us; speedup vs baseline: 3.4689x; 2.7026x over previous
//
#include <hip/hip_runtime.h>
#include <math.h>

#define NPTS 1024
#define CAND 224   // 7*32
#define KEFF 64
#define BATCH 2
#define NEGV -1e30f
#define PLANE (BATCH * NPTS * CAND)
#define NBLK 512
#define BAR_STRIDE 16   // 64B per arrival flag (no false sharing)

// R5 = R4 fusion with the grid barrier REDESIGNED.
// R4 post-mortem: 84us/barrier. Causes: (1) ACQUIRE atomic load inside the poll loop
// -> continuous cache-invalidate ops from 512 spinners; (2) 512 same-line atomic RMWs
// serialized at the cross-XCD coherence point. Fix: padded per-block arrival flags
// (relaxed stores), master block polls relaxed, single release flag, ONE acquire fence
// per block AFTER the poll exits. No RMW anywhere.

// ================================================================ weight prep (+ barrier init)
__global__ __launch_bounds__(256) void kprep(const float* __restrict__ w0, const float* __restrict__ w1,
                                             const float* __restrict__ w2, const float* __restrict__ w3,
                                             const float* __restrict__ wl, float* __restrict__ wt,
                                             unsigned* __restrict__ bar) {
    __shared__ float tA[32][33];
    __shared__ float tB[32][33];
    int id = blockIdx.x;
    int t = threadIdx.x;
    // zero the whole barrier region every launch (arrival flags + release flag)
    for (int i = id * 256 + t; i < NBLK * BAR_STRIDE + BAR_STRIDE; i += 204 * 256)
        bar[i] = 0u;
    int row = t >> 5, col = t & 31;
    const float* W = w0; int Cin = 256, Co = 128; float* WtA = wt; float* WtB = wt + 32768;
    int tc = 0, to = 0; bool isWL = false;
    if (id < 32)      { int r = id;      tc = r >> 2; to = r & 3; }
    else if (id < 48) { W = w1; Cin = 128; Co = 128; WtA = wt + 65536;  WtB = wt + 81920;  int r = id - 32; tc = r >> 2; to = r & 3; }
    else if (id < 56) { W = w2; Cin = 128; Co = 64;  WtA = wt + 98304;  WtB = wt + 106496; int r = id - 48; tc = r >> 1; to = r & 1; }
    else if (id < 60) { W = w3; Cin = 64;  Co = 64;  WtA = wt + 114688; WtB = wt + 118784; int r = id - 56; tc = r >> 1; to = r & 1; }
    else { isWL = true; int r = id - 60; tc = r / 12; to = r % 12; }
    if (!isWL) {
#pragma unroll
        for (int r = 0; r < 4; ++r) {
            int o = to * 32 + row + r * 8;
            int c = tc * 32 + col;
            float va = W[(size_t)o * 2 * Cin + c];
            tA[row + r * 8][col] = va;
            tB[row + r * 8][col] = W[(size_t)o * 2 * Cin + Cin + c] - va;
        }
        __syncthreads();
#pragma unroll
        for (int r = 0; r < 4; ++r) {
            int c = tc * 32 + row + r * 8;
            int o = to * 32 + col;
            WtA[(size_t)c * Co + o] = tA[col][row + r * 8];
            WtB[(size_t)c * Co + o] = tB[col][row + r * 8];
        }
    } else {
        float* wlT = wt + 122880;
#pragma unroll
        for (int r = 0; r < 4; ++r) {
            int o = to * 32 + row + r * 8;
            int c = tc * 32 + col;
            tA[row + r * 8][col] = wl[(size_t)o * 384 + c];
        }
        __syncthreads();
#pragma unroll
        for (int r = 0; r < 4; ++r) {
            int c = tc * 32 + row + r * 8;
            int o = to * 32 + col;
            wlT[(size_t)c * 384 + o] = tA[col][row + r * 8];
        }
    }
}

// ================================================================ grid barrier (flag-based, no RMW, relaxed polls)
__device__ __forceinline__ void gbar(unsigned* bar, unsigned ep) {
    __syncthreads();   // block done with stage; each wave's stores drained (vmcnt) by barrier semantics
    const int t = threadIdx.x;
    const int bid = blockIdx.x;
    unsigned* rel = bar + (size_t)NBLK * BAR_STRIDE;
    if (bid == 0) {
        if (t == 0) {
            __builtin_amdgcn_fence(__ATOMIC_RELEASE, "agent");    // flush this block's dirty lines
            __hip_atomic_store(&bar[0], ep, __ATOMIC_RELAXED, __HIP_MEMORY_SCOPE_AGENT);
        }
        // 256 threads poll the 512 arrival slots (relaxed — no invalidates in loop)
        for (int s = t; s < NBLK; s += 256) {
            while (__hip_atomic_load(&bar[(size_t)s * BAR_STRIDE], __ATOMIC_RELAXED, __HIP_MEMORY_SCOPE_AGENT) < ep)
                __builtin_amdgcn_s_sleep(2);
        }
        __syncthreads();
        if (t == 0) {
            __hip_atomic_store(rel, ep, __ATOMIC_RELAXED, __HIP_MEMORY_SCOPE_AGENT);
            __builtin_amdgcn_fence(__ATOMIC_ACQUIRE, "agent");    // one acquire for this block
        }
        __syncthreads();
    } else {
        if (t == 0) {
            __builtin_amdgcn_fence(__ATOMIC_RELEASE, "agent");    // flush this block's dirty lines
            __hip_atomic_store(&bar[(size_t)bid * BAR_STRIDE], ep, __ATOMIC_RELAXED, __HIP_MEMORY_SCOPE_AGENT);
            while (__hip_atomic_load(rel, __ATOMIC_RELAXED, __HIP_MEMORY_SCOPE_AGENT) < ep)
                __builtin_amdgcn_s_sleep(2);
            __builtin_amdgcn_fence(__ATOMIC_ACQUIRE, "agent");    // one acquire AFTER poll exits
        }
        __syncthreads();
    }
}

// ================================================================ select stage (per layer)
template<int NCH>
__device__ __forceinline__ void sel_stage(const float* __restrict__ Dp, const float* __restrict__ sq,
                                          int* __restrict__ idxo, float* smem, int bid, int t) {
    unsigned long long* Dsh = (unsigned long long*)smem;
    int wv = t >> 6, ln = t & 63;
#pragma unroll 1
    for (int job = bid; job < 512; job += NBLK) {
        int b = job >> 8;
        int n = (job & 255) * 4 + wv;
        int i = n >> 5;
        float sqn = sq[b * NPTS + n];
        float pr[4][NCH];
        float sqw[4];
#pragma unroll
        for (int j = 0; j < 4; ++j) {
            int w = ln + 64 * j;
            if (w < CAND) {
                size_t off = ((size_t)b * NPTS + n) * CAND + w;
#pragma unroll
                for (int ch = 0; ch < NCH; ++ch)
                    pr[j][ch] = Dp[off + (size_t)ch * PLANE];
                int wb = i - 3 + (w >> 5);
                int wbc = wb < 0 ? 0 : (wb > 31 ? 31 : wb);
                sqw[j] = sq[b * NPTS + wbc * 32 + (w & 31)];
            }
        }
        unsigned long long kj[4];
#pragma unroll
        for (int j = 0; j < 4; ++j) {
            int w = ln + 64 * j;
            if (w < CAND) {
                float s = 0.f;
#pragma unroll
                for (int ch = 0; ch < NCH; ++ch) s += pr[j][ch];
                int wb = i - 3 + (w >> 5);
                bool valid = (wb >= 0) && (wb < 32);
                float d = 2.f * s - sqn - sqw[j];
                d = valid ? d : NEGV;
                unsigned u = __float_as_uint(d);
                u ^= ((unsigned)((int)u >> 31)) | 0x80000000u;
                unsigned long long key = ((unsigned long long)u << 8) | (unsigned long long)(255 - w);
                kj[j] = key;
                Dsh[wv * 224 + w] = key;
            } else {
                kj[j] = 0ull;
            }
        }
        __syncthreads();
        int cnt[4] = {0, 0, 0, 0};
        const ulonglong2* row = (const ulonglong2*)(Dsh + wv * 224);
#pragma unroll 2
        for (int w2 = 0; w2 < 112; w2 += 4) {
            ulonglong2 k0 = row[w2], k1 = row[w2 + 1], k2 = row[w2 + 2], k3 = row[w2 + 3];
#pragma unroll
            for (int j = 0; j < 4; ++j) {
                unsigned long long kk = kj[j];
                cnt[j] += (int)(k0.x > kk) + (int)(k0.y > kk) + (int)(k1.x > kk) + (int)(k1.y > kk)
                        + (int)(k2.x > kk) + (int)(k2.y > kk) + (int)(k3.x > kk) + (int)(k3.y > kk);
            }
        }
#pragma unroll
        for (int j = 0; j < 4; ++j) {
            int w = ln + 64 * j;
            if (w < CAND && cnt[j] < KEFF)
                idxo[((size_t)b * KEFF + cnt[j]) * NPTS + n] = (i - 3) * 32 + w;   // k-major
        }
        __syncthreads();
    }
}

// ================================================================ the fused persistent kernel
struct MP {
    const float* x;
    const float* g0; const float* g1; const float* g2; const float* g3;
    const float* be0; const float* be1; const float* be2; const float* be3;
    float* xconM; float* A; float* Bv; float* sq; float* Dp; float* part; float* wt;
    int* idx; unsigned* bar; float* out;
};

__global__ __launch_bounds__(256, 3) void kmega(MP P) {
    __shared__ __align__(16) float smem[7168];
    __shared__ float shsc[384];
    __shared__ float shsh[384];
    const int t = threadIdx.x;
    const int bid = blockIdx.x;
    unsigned ep = 0;

#pragma unroll 1
    for (int l = 0; l < 4; ++l) {
        const int Cin   = (l == 0) ? 256 : (l == 3) ? 64 : 128;
        const int Co    = (l < 2) ? 128 : 64;
        const int nch   = (l == 0) ? 8 : (l == 3) ? 2 : 4;
        const int nchLg = (l == 0) ? 3 : (l == 3) ? 1 : 2;
        const int chOut = (l == 0) ? 0 : (l == 1) ? 128 : (l == 2) ? 256 : 320;
        const float* xin = (l == 0) ? P.x : P.xconM + (size_t)(l - 1) * 131072;
        const int bstride = (l == 0) ? 262144 : 393216;
        const float* WtA = P.wt + ((l == 0) ? 0 : (l == 1) ? 65536 : (l == 2) ? 98304 : 114688);
        const float* WtB = P.wt + ((l == 0) ? 32768 : (l == 1) ? 81920 : (l == 2) ? 106496 : 118784);

        // BN scale/shift for this layer's input (prev layer's 4 partials per channel)
        if (l > 0 && t < Cin) {
            const float* pp = P.part + (size_t)(l - 1) * 1024;
            const float* gPr = (l == 1) ? P.g0  : (l == 2) ? P.g1  : P.g2;
            const float* bPr = (l == 1) ? P.be0 : (l == 2) ? P.be1 : P.be2;
            float s  = pp[4 * t]     + pp[4 * t + 2]     + pp[4 * (Cin + t)]     + pp[4 * (Cin + t) + 2];
            float s2 = pp[4 * t + 1] + pp[4 * t + 3]     + pp[4 * (Cin + t) + 1] + pp[4 * (Cin + t) + 3];
            const float invc = 1.f / 131072.f;
            float mu = s * invc;
            float var = s2 * invc - mu * mu;
            float rs = rsqrtf(var + 1e-5f);
            float sc = gPr[t] * rs;
            shsc[t] = sc;
            shsh[t] = bPr[t] - mu * sc;
        }
        __syncthreads();

        // ---------------- gemm stage (role A: A/Bv/sq tiles; role B: gram partials)
        const int nOT = Co >> 6;
        const int notLg = nOT - 1;          // 2->1, 1->0
        const int nABx = 32 * nOT * BATCH;
        const int nJobs = nABx + nch * 32 * BATCH;
#pragma unroll 1
        for (int job = bid; job < nJobs; job += NBLK) {
            if (job < nABx) {
                int nt = job & 31; int rest = job >> 5;
                int ot = rest & (nOT - 1); int b = rest >> notLg;
                int tn2 = (t & 15) * 2, to4 = (t >> 4) * 4;
                int n0 = nt * 32, o0 = ot * 64;
                const float* xb = xin + (size_t)b * bstride + n0;
                float* Xs = smem; float* Wta = smem + 1024; float* Wtb = smem + 3200;
                float2 a2[4], b2[4], s2v;
#pragma unroll
                for (int q = 0; q < 4; ++q) { a2[q] = make_float2(0.f, 0.f); b2[q] = make_float2(0.f, 0.f); }
                s2v = make_float2(0.f, 0.f);
                int xcc0 = t >> 5, xnn = t & 31;
                int wcc0 = t >> 6, woo = t & 63;
                for (int c0 = 0; c0 < Cin; c0 += 32) {
                    float rx[4], ra[8], rb[8];
#pragma unroll
                    for (int k = 0; k < 4; ++k)
                        rx[k] = xb[(size_t)(c0 + xcc0 + k * 8) * NPTS + xnn];
#pragma unroll
                    for (int k = 0; k < 8; ++k) {
                        ra[k] = WtA[(size_t)(c0 + wcc0 + k * 4) * Co + o0 + woo];
                        rb[k] = WtB[(size_t)(c0 + wcc0 + k * 4) * Co + o0 + woo];
                    }
                    if (l > 0) {
#pragma unroll
                        for (int k = 0; k < 4; ++k) {
                            int cc = xcc0 + k * 8;
                            float y = fmaf(rx[k], shsc[c0 + cc], shsh[c0 + cc]);
                            rx[k] = y >= 0.f ? y : 0.2f * y;
                        }
                    }
                    __syncthreads();
#pragma unroll
                    for (int k = 0; k < 4; ++k)
                        Xs[(xcc0 + k * 8) * 32 + xnn] = rx[k];
#pragma unroll
                    for (int k = 0; k < 8; ++k) {
                        Wta[(wcc0 + k * 4) * 68 + woo] = ra[k];
                        Wtb[(wcc0 + k * 4) * 68 + woo] = rb[k];
                    }
                    __syncthreads();
#pragma unroll 8
                    for (int cc = 0; cc < 32; ++cc) {
                        float2 xv = *(const float2*)&Xs[cc * 32 + tn2];
                        float4 wa = *(const float4*)&Wta[cc * 68 + to4];
                        float4 wb = *(const float4*)&Wtb[cc * 68 + to4];
                        s2v.x = fmaf(xv.x, xv.x, s2v.x);
                        s2v.y = fmaf(xv.y, xv.y, s2v.y);
                        float wav[4] = {wa.x, wa.y, wa.z, wa.w};
                        float wbv[4] = {wb.x, wb.y, wb.z, wb.w};
#pragma unroll
                        for (int q = 0; q < 4; ++q) {
                            a2[q].x = fmaf(wav[q], xv.x, a2[q].x);
                            a2[q].y = fmaf(wav[q], xv.y, a2[q].y);
                            b2[q].x = fmaf(wbv[q], xv.x, b2[q].x);
                            b2[q].y = fmaf(wbv[q], xv.y, b2[q].y);
                        }
                    }
                }
                int n = n0 + tn2;
                if (ot == 0 && to4 == 0)
                    *(float2*)&P.sq[b * NPTS + n] = s2v;
#pragma unroll
                for (int q = 0; q < 4; ++q) {
                    int o = o0 + to4 + q;
                    size_t off = ((size_t)(b * Co + o)) * NPTS + n;
                    *(float2*)&P.A[off] = a2[q];
                    *(float2*)&P.Bv[off] = b2[q];
                }
            } else {
                int id2 = job - nABx;
                int chunk = id2 & (nch - 1); int rest = id2 >> nchLg;
                int i = rest & 31; int b = rest >> 5;
                int c0 = chunk * 32;
                const float* xb = xin + (size_t)b * bstride;
                float* Xc = smem;
                int q = t >> 3;
                int wg = t & 7;
                float r[28];
                int rcc[28], rw[28];
#pragma unroll
                for (int k = 0; k < 28; ++k) {
                    int e = t + k * 256;
                    int cc = e / CAND;
                    int w  = e - cc * CAND;
                    rcc[k] = cc; rw[k] = w;
                    int wb = i - 3 + (w >> 5);
                    wb = wb < 0 ? 0 : (wb > 31 ? 31 : wb);
                    r[k] = xb[(size_t)(c0 + cc) * NPTS + wb * 32 + (w & 31)];
                }
                if (l > 0) {
#pragma unroll
                    for (int k = 0; k < 28; ++k) {
                        float y = fmaf(r[k], shsc[c0 + rcc[k]], shsh[c0 + rcc[k]]);
                        r[k] = y >= 0.f ? y : 0.2f * y;
                    }
                }
#pragma unroll
                for (int k = 0; k < 28; ++k)
                    Xc[rcc[k] * CAND + rw[k]] = r[k];
                __syncthreads();
                float acc[28];
#pragma unroll
                for (int j = 0; j < 28; ++j) acc[j] = 0.f;
                for (int cc = 0; cc < 32; ++cc) {
                    float qv = Xc[cc * CAND + 96 + q];
                    const float4* rowp = (const float4*)&Xc[cc * CAND + wg * 28];
#pragma unroll
                    for (int j4 = 0; j4 < 7; ++j4) {
                        float4 v = rowp[j4];
                        acc[j4 * 4 + 0] = fmaf(qv, v.x, acc[j4 * 4 + 0]);
                        acc[j4 * 4 + 1] = fmaf(qv, v.y, acc[j4 * 4 + 1]);
                        acc[j4 * 4 + 2] = fmaf(qv, v.z, acc[j4 * 4 + 2]);
                        acc[j4 * 4 + 3] = fmaf(qv, v.w, acc[j4 * 4 + 3]);
                    }
                }
                int n = i * 32 + q;
                size_t base = (((size_t)chunk * BATCH + b) * NPTS + n) * CAND + wg * 28;
                float4* outp = (float4*)&P.Dp[base];
#pragma unroll
                for (int j4 = 0; j4 < 7; ++j4)
                    outp[j4] = make_float4(acc[j4 * 4], acc[j4 * 4 + 1], acc[j4 * 4 + 2], acc[j4 * 4 + 3]);
            }
            __syncthreads();   // job-end: LDS reuse safe
        }
        gbar(P.bar, ++ep);

        // ---------------- select stage
        if (nch == 8)      sel_stage<8>(P.Dp, P.sq, P.idx, smem, bid, t);
        else if (nch == 4) sel_stage<4>(P.Dp, P.sq, P.idx, smem, bid, t);
        else               sel_stage<2>(P.Dp, P.sq, P.idx, smem, bid, t);
        gbar(P.bar, ++ep);

        // ---------------- agg stage (n split into 2 halves -> Co*4 jobs)
        const int CoLg = (Co == 128) ? 7 : 6;
#pragma unroll 1
        for (int job = bid; job < Co * 4; job += NBLK) {
            int o = job & (Co - 1); int rest = job >> CoLg;
            int b = rest & 1; int h = rest >> 1;
            float* Ash = smem;
            float* red = smem + 1024;
            size_t rowoff = (size_t)(b * Co + o) * NPTS;
            {
                float rA[4];
#pragma unroll
                for (int r = 0; r < 4; ++r) rA[r] = P.A[rowoff + r * 256 + t];
#pragma unroll
                for (int r = 0; r < 4; ++r) Ash[r * 256 + t] = rA[r];
            }
            __syncthreads();
            float sum = 0.f, sumsq = 0.f;
#pragma unroll 1
            for (int r = 0; r < 2; ++r) {
                int n = h * 512 + r * 256 + t;
                const int* ip = P.idx + (size_t)b * KEFF * NPTS + n;
                float s1 = 0.f, s2 = 0.f, mx = -3.4e38f;
#pragma unroll
                for (int kb = 0; kb < 4; ++kb) {
                    int iv[16];
#pragma unroll
                    for (int m = 0; m < 16; ++m)
                        iv[m] = ip[(size_t)(kb * 16 + m) * NPTS];
                    float av[16];
#pragma unroll
                    for (int m = 0; m < 16; ++m) av[m] = Ash[iv[m]];
#pragma unroll
                    for (int m = 0; m < 16; m += 4) {
                        s1 += av[m] + av[m+1] + av[m+2] + av[m+3];
                        s2 += av[m]*av[m] + av[m+1]*av[m+1] + av[m+2]*av[m+2] + av[m+3]*av[m+3];
                        mx = fmaxf(mx, fmaxf(fmaxf(av[m], av[m+1]), fmaxf(av[m+2], av[m+3])));
                    }
                }
                float bv = P.Bv[rowoff + n];
                P.xconM[((size_t)b * 384 + chOut + o) * NPTS + n] = mx + bv;
                sum   += s1 + 64.f * bv;
                sumsq += s2 + 2.f * bv * s1 + 64.f * bv * bv;
            }
            red[t] = sum; __syncthreads();
            for (int s = 128; s > 0; s >>= 1) { if (t < s) red[t] += red[t + s]; __syncthreads(); }
            if (t == 0) P.part[(size_t)l * 1024 + ((b * Co + o) * 2 + h) * 2 + 0] = red[0];
            __syncthreads();
            red[t] = sumsq; __syncthreads();
            for (int s = 128; s > 0; s >>= 1) { if (t < s) red[t] += red[t + s]; __syncthreads(); }
            if (t == 0) P.part[(size_t)l * 1024 + ((b * Co + o) * 2 + h) * 2 + 1] = red[0];
            __syncthreads();
        }
        gbar(P.bar, ++ep);
    }

    // ---------------- final GEMM (64o x 32n tiles -> 384 jobs)
    for (int ch = t; ch < 384; ch += 256) {
        const float* pl; const float* gl; const float* bl; int o, Col;
        if (ch < 128)      { pl = P.part;         gl = P.g0; bl = P.be0; o = ch;       Col = 128; }
        else if (ch < 256) { pl = P.part + 1024;  gl = P.g1; bl = P.be1; o = ch - 128; Col = 128; }
        else if (ch < 320) { pl = P.part + 2048;  gl = P.g2; bl = P.be2; o = ch - 256; Col = 64;  }
        else               { pl = P.part + 3072;  gl = P.g3; bl = P.be3; o = ch - 320; Col = 64;  }
        float s  = pl[4 * o]     + pl[4 * o + 2]     + pl[4 * (Col + o)]     + pl[4 * (Col + o) + 2];
        float s2 = pl[4 * o + 1] + pl[4 * o + 3]     + pl[4 * (Col + o) + 1] + pl[4 * (Col + o) + 3];
        const float invc = 1.f / 131072.f;
        float mu = s * invc;
        float var = s2 * invc - mu * mu;
        float rs = rsqrtf(var + 1e-5f);
        float sc = gl[o] * rs;
        shsc[ch] = sc;
        shsh[ch] = bl[o] - mu * sc;
    }
    __syncthreads();
    const float* wlT = P.wt + 122880;
#pragma unroll 1
    for (int job = bid; job < 384; job += NBLK) {
        int nt = job & 31; int rest = job >> 5;
        int ot = rest % 6; int b = rest / 6;
        int n0 = nt * 32, o0 = ot * 64;
        int tn2 = (t & 15) * 2, to4 = (t >> 4) * 4;
        int nn = t & 31, cx0 = t >> 5;
        int woo = t & 63, cw0 = t >> 6;
        float* Xs = smem;
        float* Wl = smem + 1024;
        float2 acc2[4];
#pragma unroll
        for (int i = 0; i < 4; ++i) acc2[i] = make_float2(0.f, 0.f);
        for (int c0 = 0; c0 < 384; c0 += 32) {
            float rx[4], rw[8];
#pragma unroll
            for (int k = 0; k < 4; ++k)
                rx[k] = P.xconM[((size_t)b * 384 + c0 + cx0 + k * 8) * NPTS + n0 + nn];
#pragma unroll
            for (int k = 0; k < 8; ++k)
                rw[k] = wlT[(size_t)(c0 + cw0 + k * 4) * 384 + o0 + woo];
#pragma unroll
            for (int k = 0; k < 4; ++k) {
                int cc = c0 + cx0 + k * 8;
                float y = fmaf(rx[k], shsc[cc], shsh[cc]);
                rx[k] = y >= 0.f ? y : 0.2f * y;
            }
            __syncthreads();
#pragma unroll
            for (int k = 0; k < 4; ++k)
                Xs[(cx0 + k * 8) * 32 + nn] = rx[k];
#pragma unroll
            for (int k = 0; k < 8; ++k)
                Wl[(cw0 + k * 4) * 68 + woo] = rw[k];
            __syncthreads();
#pragma unroll 8
            for (int cc = 0; cc < 32; ++cc) {
                float2 xv = *(const float2*)&Xs[cc * 32 + tn2];
                float4 wv = *(const float4*)&Wl[cc * 68 + to4];
                float wvv[4] = {wv.x, wv.y, wv.z, wv.w};
#pragma unroll
                for (int i = 0; i < 4; ++i) {
                    acc2[i].x = fmaf(wvv[i], xv.x, acc2[i].x);
                    acc2[i].y = fmaf(wvv[i], xv.y, acc2[i].y);
                }
            }
        }
#pragma unroll
        for (int i = 0; i < 4; ++i)
            *(float2*)&P.out[((size_t)b * 384 + o0 + to4 + i) * NPTS + n0 + tn2] = acc2[i];
        __syncthreads();
    }
}

extern "C" void kernel_launch(void* const* d_in, const int* in_sizes, int n_in,
                              void* d_out, int out_size, void* d_ws, size_t ws_size,
                              hipStream_t stream) {
    const float* x  = (const float*)d_in[0];
    const float* w[4]  = {(const float*)d_in[1], (const float*)d_in[4], (const float*)d_in[7], (const float*)d_in[10]};
    const float* g[4]  = {(const float*)d_in[2], (const float*)d_in[5], (const float*)d_in[8], (const float*)d_in[11]};
    const float* be[4] = {(const float*)d_in[3], (const float*)d_in[6], (const float*)d_in[9], (const float*)d_in[12]};
    const float* wl = (const float*)d_in[13];

    float* ws    = (float*)d_ws;
    float* xconM = ws;                       // 786432
    float* A     = xconM + 786432;           // 262144
    float* Bv    = A + 262144;               // 262144
    float* sq    = Bv + 262144;              // 2048
    float* Dp    = sq + 2048;                // 8 planes * 458752 = 3670016
    float* part  = Dp + 3670016;             // 4096 (4 layers x 1024)
    float* wt    = part + 4096;              // 270336
    int*   idx   = (int*)(wt + 270336);      // 131072 ints (k-major: [b][k][n])
    unsigned* bar = (unsigned*)(idx + 131072);  // (NBLK+1)*BAR_STRIDE uints

    kprep<<<204, 256, 0, stream>>>(w[0], w[1], w[2], w[3], wl, wt, bar);

    MP mp;
    mp.x = x;
    mp.g0 = g[0]; mp.g1 = g[1]; mp.g2 = g[2]; mp.g3 = g[3];
    mp.be0 = be[0]; mp.be1 = be[1]; mp.be2 = be[2]; mp.be3 = be[3];
    mp.xconM = xconM; mp.A = A; mp.Bv = Bv; mp.sq = sq; mp.Dp = Dp;
    mp.part = part; mp.wt = wt; mp.idx = idx; mp.bar = bar;
    mp.out = (float*)d_out;
    kmega<<<NBLK, 256, 0, stream>>>(mp);
}

// Round 6
// 334.859 us; speedup vs baseline: 4.8454x; 1.3968x over previous
//
#include <hip/hip_runtime.h>
#include <math.h>

#define NPTS 1024
#define CAND 224   // 7*32
#define KEFF 64
#define BATCH 2
#define NEGV -1e30f
#define PLANE (BATCH * NPTS * CAND)
#define NBLK 512
#define BAR_STRIDE 16   // 64B per arrival flag (no false sharing)

// R6 = R5 with FENCE-FREE coherence. R5 post-mortem: ~23us/barrier left; per-block
// agent fences emit buffer_wbl2 (release) + buffer_inv (acquire) -> 64x redundant L2
// writebacks per XCD and a FULL L2 invalidate per barrier (FETCH_SIZE 55.8MB of
// re-fetches). Fix: all cross-stage buffers (A,Bv,sq,Dp,idx,xconM,part,flags) use
// agent-coherent relaxed atomics (sc0 sc1: bypass L1/L2, coherent at LLC); immutable
// data (x, weights) keeps normal cached loads and now SURVIVES across stages.
// Barrier = __syncthreads (drains vmcnt; sc1 stores ack at coherent point) + relaxed
// arrival/poll. Zero cache-maintenance instructions.

#define AG __HIP_MEMORY_SCOPE_AGENT
__device__ __forceinline__ float cld(const float* p) {
    return __hip_atomic_load((float*)p, __ATOMIC_RELAXED, AG);
}
__device__ __forceinline__ void cst(float* p, float v) {
    __hip_atomic_store(p, v, __ATOMIC_RELAXED, AG);
}
__device__ __forceinline__ int cldi(const int* p) {
    return __hip_atomic_load((int*)p, __ATOMIC_RELAXED, AG);
}
__device__ __forceinline__ void csti(int* p, int v) {
    __hip_atomic_store(p, v, __ATOMIC_RELAXED, AG);
}
__device__ __forceinline__ void cst2(float* p, float2 v) {
    union { float2 f; unsigned long long u; } c; c.f = v;
    __hip_atomic_store((unsigned long long*)p, c.u, __ATOMIC_RELAXED, AG);
}

// ================================================================ weight prep (+ barrier init)
__global__ __launch_bounds__(256) void kprep(const float* __restrict__ w0, const float* __restrict__ w1,
                                             const float* __restrict__ w2, const float* __restrict__ w3,
                                             const float* __restrict__ wl, float* __restrict__ wt,
                                             unsigned* __restrict__ bar) {
    __shared__ float tA[32][33];
    __shared__ float tB[32][33];
    int id = blockIdx.x;
    int t = threadIdx.x;
    // zero the whole barrier region every launch (arrival flags + release flag)
    for (int i = id * 256 + t; i < NBLK * BAR_STRIDE + BAR_STRIDE; i += 204 * 256)
        bar[i] = 0u;
    int row = t >> 5, col = t & 31;
    const float* W = w0; int Cin = 256, Co = 128; float* WtA = wt; float* WtB = wt + 32768;
    int tc = 0, to = 0; bool isWL = false;
    if (id < 32)      { int r = id;      tc = r >> 2; to = r & 3; }
    else if (id < 48) { W = w1; Cin = 128; Co = 128; WtA = wt + 65536;  WtB = wt + 81920;  int r = id - 32; tc = r >> 2; to = r & 3; }
    else if (id < 56) { W = w2; Cin = 128; Co = 64;  WtA = wt + 98304;  WtB = wt + 106496; int r = id - 48; tc = r >> 1; to = r & 1; }
    else if (id < 60) { W = w3; Cin = 64;  Co = 64;  WtA = wt + 114688; WtB = wt + 118784; int r = id - 56; tc = r >> 1; to = r & 1; }
    else { isWL = true; int r = id - 60; tc = r / 12; to = r % 12; }
    if (!isWL) {
#pragma unroll
        for (int r = 0; r < 4; ++r) {
            int o = to * 32 + row + r * 8;
            int c = tc * 32 + col;
            float va = W[(size_t)o * 2 * Cin + c];
            tA[row + r * 8][col] = va;
            tB[row + r * 8][col] = W[(size_t)o * 2 * Cin + Cin + c] - va;
        }
        __syncthreads();
#pragma unroll
        for (int r = 0; r < 4; ++r) {
            int c = tc * 32 + row + r * 8;
            int o = to * 32 + col;
            WtA[(size_t)c * Co + o] = tA[col][row + r * 8];
            WtB[(size_t)c * Co + o] = tB[col][row + r * 8];
        }
    } else {
        float* wlT = wt + 122880;
#pragma unroll
        for (int r = 0; r < 4; ++r) {
            int o = to * 32 + row + r * 8;
            int c = tc * 32 + col;
            tA[row + r * 8][col] = wl[(size_t)o * 384 + c];
        }
        __syncthreads();
#pragma unroll
        for (int r = 0; r < 4; ++r) {
            int c = tc * 32 + row + r * 8;
            int o = to * 32 + col;
            wlT[(size_t)c * 384 + o] = tA[col][row + r * 8];
        }
    }
}

// ================================================================ grid barrier (fence-free: coherent flags only)
__device__ __forceinline__ void gbar(unsigned* bar, unsigned ep) {
    __syncthreads();   // hw-drains vmcnt(0): all sc1 data stores ack'd at the coherent point
    const int t = threadIdx.x;
    const int bid = blockIdx.x;
    unsigned* rel = bar + (size_t)NBLK * BAR_STRIDE;
    if (bid == 0) {
        if (t == 0)
            __hip_atomic_store(&bar[0], ep, __ATOMIC_RELAXED, AG);
        for (int s = t; s < NBLK; s += 256) {
            while (__hip_atomic_load(&bar[(size_t)s * BAR_STRIDE], __ATOMIC_RELAXED, AG) < ep)
                __builtin_amdgcn_s_sleep(1);
        }
        __syncthreads();
        if (t == 0)
            __hip_atomic_store(rel, ep, __ATOMIC_RELAXED, AG);
    } else {
        if (t == 0) {
            __hip_atomic_store(&bar[(size_t)bid * BAR_STRIDE], ep, __ATOMIC_RELAXED, AG);
            while (__hip_atomic_load(rel, __ATOMIC_RELAXED, AG) < ep)
                __builtin_amdgcn_s_sleep(1);
        }
    }
    __syncthreads();
}

// ================================================================ select stage (per layer)
template<int NCH>
__device__ __forceinline__ void sel_stage(const float* __restrict__ Dp, const float* __restrict__ sq,
                                          int* __restrict__ idxo, float* smem, int bid, int t) {
    unsigned long long* Dsh = (unsigned long long*)smem;
    int wv = t >> 6, ln = t & 63;
#pragma unroll 1
    for (int job = bid; job < 512; job += NBLK) {
        int b = job >> 8;
        int n = (job & 255) * 4 + wv;
        int i = n >> 5;
        float sqn = cld(&sq[b * NPTS + n]);
        float pr[4][NCH];
        float sqw[4];
#pragma unroll
        for (int j = 0; j < 4; ++j) {
            int w = ln + 64 * j;
            if (w < CAND) {
                size_t off = ((size_t)b * NPTS + n) * CAND + w;
#pragma unroll
                for (int ch = 0; ch < NCH; ++ch)
                    pr[j][ch] = cld(&Dp[off + (size_t)ch * PLANE]);
                int wb = i - 3 + (w >> 5);
                int wbc = wb < 0 ? 0 : (wb > 31 ? 31 : wb);
                sqw[j] = cld(&sq[b * NPTS + wbc * 32 + (w & 31)]);
            }
        }
        unsigned long long kj[4];
#pragma unroll
        for (int j = 0; j < 4; ++j) {
            int w = ln + 64 * j;
            if (w < CAND) {
                float s = 0.f;
#pragma unroll
                for (int ch = 0; ch < NCH; ++ch) s += pr[j][ch];
                int wb = i - 3 + (w >> 5);
                bool valid = (wb >= 0) && (wb < 32);
                float d = 2.f * s - sqn - sqw[j];
                d = valid ? d : NEGV;
                unsigned u = __float_as_uint(d);
                u ^= ((unsigned)((int)u >> 31)) | 0x80000000u;
                unsigned long long key = ((unsigned long long)u << 8) | (unsigned long long)(255 - w);
                kj[j] = key;
                Dsh[wv * 224 + w] = key;
            } else {
                kj[j] = 0ull;
            }
        }
        __syncthreads();
        int cnt[4] = {0, 0, 0, 0};
        const ulonglong2* row = (const ulonglong2*)(Dsh + wv * 224);
#pragma unroll 2
        for (int w2 = 0; w2 < 112; w2 += 4) {
            ulonglong2 k0 = row[w2], k1 = row[w2 + 1], k2 = row[w2 + 2], k3 = row[w2 + 3];
#pragma unroll
            for (int j = 0; j < 4; ++j) {
                unsigned long long kk = kj[j];
                cnt[j] += (int)(k0.x > kk) + (int)(k0.y > kk) + (int)(k1.x > kk) + (int)(k1.y > kk)
                        + (int)(k2.x > kk) + (int)(k2.y > kk) + (int)(k3.x > kk) + (int)(k3.y > kk);
            }
        }
#pragma unroll
        for (int j = 0; j < 4; ++j) {
            int w = ln + 64 * j;
            if (w < CAND && cnt[j] < KEFF)
                csti(&idxo[((size_t)b * KEFF + cnt[j]) * NPTS + n], (i - 3) * 32 + w);   // k-major
        }
        __syncthreads();
    }
}

// ================================================================ the fused persistent kernel
struct MP {
    const float* x;
    const float* g0; const float* g1; const float* g2; const float* g3;
    const float* be0; const float* be1; const float* be2; const float* be3;
    float* xconM; float* A; float* Bv; float* sq; float* Dp; float* part; float* wt;
    int* idx; unsigned* bar; float* out;
};

__global__ __launch_bounds__(256, 3) void kmega(MP P) {
    __shared__ __align__(16) float smem[7168];
    __shared__ float shsc[384];
    __shared__ float shsh[384];
    const int t = threadIdx.x;
    const int bid = blockIdx.x;
    unsigned ep = 0;

#pragma unroll 1
    for (int l = 0; l < 4; ++l) {
        const int Cin   = (l == 0) ? 256 : (l == 3) ? 64 : 128;
        const int Co    = (l < 2) ? 128 : 64;
        const int nch   = (l == 0) ? 8 : (l == 3) ? 2 : 4;
        const int nchLg = (l == 0) ? 3 : (l == 3) ? 1 : 2;
        const int chOut = (l == 0) ? 0 : (l == 1) ? 128 : (l == 2) ? 256 : 320;
        const float* xin = (l == 0) ? P.x : P.xconM + (size_t)(l - 1) * 131072;
        const int bstride = (l == 0) ? 262144 : 393216;
        const float* WtA = P.wt + ((l == 0) ? 0 : (l == 1) ? 65536 : (l == 2) ? 98304 : 114688);
        const float* WtB = P.wt + ((l == 0) ? 32768 : (l == 1) ? 81920 : (l == 2) ? 106496 : 118784);

        // BN scale/shift for this layer's input (prev layer's 4 partials per channel)
        if (l > 0 && t < Cin) {
            const float* pp = P.part + (size_t)(l - 1) * 1024;
            const float* gPr = (l == 1) ? P.g0  : (l == 2) ? P.g1  : P.g2;
            const float* bPr = (l == 1) ? P.be0 : (l == 2) ? P.be1 : P.be2;
            float s  = cld(&pp[4 * t])     + cld(&pp[4 * t + 2])     + cld(&pp[4 * (Cin + t)])     + cld(&pp[4 * (Cin + t) + 2]);
            float s2 = cld(&pp[4 * t + 1]) + cld(&pp[4 * t + 3])     + cld(&pp[4 * (Cin + t) + 1]) + cld(&pp[4 * (Cin + t) + 3]);
            const float invc = 1.f / 131072.f;
            float mu = s * invc;
            float var = s2 * invc - mu * mu;
            float rs = rsqrtf(var + 1e-5f);
            float sc = gPr[t] * rs;
            shsc[t] = sc;
            shsh[t] = bPr[t] - mu * sc;
        }
        __syncthreads();

        // ---------------- gemm stage (role A: A/Bv/sq tiles; role B: gram partials)
        const int nOT = Co >> 6;
        const int notLg = nOT - 1;          // 2->1, 1->0
        const int nABx = 32 * nOT * BATCH;
        const int nJobs = nABx + nch * 32 * BATCH;
#pragma unroll 1
        for (int job = bid; job < nJobs; job += NBLK) {
            if (job < nABx) {
                int nt = job & 31; int rest = job >> 5;
                int ot = rest & (nOT - 1); int b = rest >> notLg;
                int tn2 = (t & 15) * 2, to4 = (t >> 4) * 4;
                int n0 = nt * 32, o0 = ot * 64;
                const float* xb = xin + (size_t)b * bstride + n0;
                float* Xs = smem; float* Wta = smem + 1024; float* Wtb = smem + 3200;
                float2 a2[4], b2[4], s2v;
#pragma unroll
                for (int q = 0; q < 4; ++q) { a2[q] = make_float2(0.f, 0.f); b2[q] = make_float2(0.f, 0.f); }
                s2v = make_float2(0.f, 0.f);
                int xcc0 = t >> 5, xnn = t & 31;
                int wcc0 = t >> 6, woo = t & 63;
                for (int c0 = 0; c0 < Cin; c0 += 32) {
                    float rx[4], ra[8], rb[8];
#pragma unroll
                    for (int k = 0; k < 4; ++k)
                        rx[k] = cld(&xb[(size_t)(c0 + xcc0 + k * 8) * NPTS + xnn]);
#pragma unroll
                    for (int k = 0; k < 8; ++k) {
                        ra[k] = WtA[(size_t)(c0 + wcc0 + k * 4) * Co + o0 + woo];
                        rb[k] = WtB[(size_t)(c0 + wcc0 + k * 4) * Co + o0 + woo];
                    }
                    if (l > 0) {
#pragma unroll
                        for (int k = 0; k < 4; ++k) {
                            int cc = xcc0 + k * 8;
                            float y = fmaf(rx[k], shsc[c0 + cc], shsh[c0 + cc]);
                            rx[k] = y >= 0.f ? y : 0.2f * y;
                        }
                    }
                    __syncthreads();
#pragma unroll
                    for (int k = 0; k < 4; ++k)
                        Xs[(xcc0 + k * 8) * 32 + xnn] = rx[k];
#pragma unroll
                    for (int k = 0; k < 8; ++k) {
                        Wta[(wcc0 + k * 4) * 68 + woo] = ra[k];
                        Wtb[(wcc0 + k * 4) * 68 + woo] = rb[k];
                    }
                    __syncthreads();
#pragma unroll 8
                    for (int cc = 0; cc < 32; ++cc) {
                        float2 xv = *(const float2*)&Xs[cc * 32 + tn2];
                        float4 wa = *(const float4*)&Wta[cc * 68 + to4];
                        float4 wb = *(const float4*)&Wtb[cc * 68 + to4];
                        s2v.x = fmaf(xv.x, xv.x, s2v.x);
                        s2v.y = fmaf(xv.y, xv.y, s2v.y);
                        float wav[4] = {wa.x, wa.y, wa.z, wa.w};
                        float wbv[4] = {wb.x, wb.y, wb.z, wb.w};
#pragma unroll
                        for (int q = 0; q < 4; ++q) {
                            a2[q].x = fmaf(wav[q], xv.x, a2[q].x);
                            a2[q].y = fmaf(wav[q], xv.y, a2[q].y);
                            b2[q].x = fmaf(wbv[q], xv.x, b2[q].x);
                            b2[q].y = fmaf(wbv[q], xv.y, b2[q].y);
                        }
                    }
                }
                int n = n0 + tn2;
                if (ot == 0 && to4 == 0)
                    cst2(&P.sq[b * NPTS + n], s2v);
#pragma unroll
                for (int q = 0; q < 4; ++q) {
                    int o = o0 + to4 + q;
                    size_t off = ((size_t)(b * Co + o)) * NPTS + n;
                    cst2(&P.A[off], a2[q]);
                    cst2(&P.Bv[off], b2[q]);
                }
            } else {
                int id2 = job - nABx;
                int chunk = id2 & (nch - 1); int rest = id2 >> nchLg;
                int i = rest & 31; int b = rest >> 5;
                int c0 = chunk * 32;
                const float* xb = xin + (size_t)b * bstride;
                float* Xc = smem;
                int q = t >> 3;
                int wg = t & 7;
                float r[28];
                int rcc[28], rw[28];
#pragma unroll
                for (int k = 0; k < 28; ++k) {
                    int e = t + k * 256;
                    int cc = e / CAND;
                    int w  = e - cc * CAND;
                    rcc[k] = cc; rw[k] = w;
                    int wb = i - 3 + (w >> 5);
                    wb = wb < 0 ? 0 : (wb > 31 ? 31 : wb);
                    r[k] = cld(&xb[(size_t)(c0 + cc) * NPTS + wb * 32 + (w & 31)]);
                }
                if (l > 0) {
#pragma unroll
                    for (int k = 0; k < 28; ++k) {
                        float y = fmaf(r[k], shsc[c0 + rcc[k]], shsh[c0 + rcc[k]]);
                        r[k] = y >= 0.f ? y : 0.2f * y;
                    }
                }
#pragma unroll
                for (int k = 0; k < 28; ++k)
                    Xc[rcc[k] * CAND + rw[k]] = r[k];
                __syncthreads();
                float acc[28];
#pragma unroll
                for (int j = 0; j < 28; ++j) acc[j] = 0.f;
                for (int cc = 0; cc < 32; ++cc) {
                    float qv = Xc[cc * CAND + 96 + q];
                    const float4* rowp = (const float4*)&Xc[cc * CAND + wg * 28];
#pragma unroll
                    for (int j4 = 0; j4 < 7; ++j4) {
                        float4 v = rowp[j4];
                        acc[j4 * 4 + 0] = fmaf(qv, v.x, acc[j4 * 4 + 0]);
                        acc[j4 * 4 + 1] = fmaf(qv, v.y, acc[j4 * 4 + 1]);
                        acc[j4 * 4 + 2] = fmaf(qv, v.z, acc[j4 * 4 + 2]);
                        acc[j4 * 4 + 3] = fmaf(qv, v.w, acc[j4 * 4 + 3]);
                    }
                }
                int n = i * 32 + q;
                size_t base = (((size_t)chunk * BATCH + b) * NPTS + n) * CAND + wg * 28;
                float* op = &P.Dp[base];
#pragma unroll
                for (int j4 = 0; j4 < 7; ++j4) {
                    cst2(op + j4 * 4,     make_float2(acc[j4 * 4],     acc[j4 * 4 + 1]));
                    cst2(op + j4 * 4 + 2, make_float2(acc[j4 * 4 + 2], acc[j4 * 4 + 3]));
                }
            }
            __syncthreads();   // job-end: LDS reuse safe
        }
        gbar(P.bar, ++ep);

        // ---------------- select stage
        if (nch == 8)      sel_stage<8>(P.Dp, P.sq, P.idx, smem, bid, t);
        else if (nch == 4) sel_stage<4>(P.Dp, P.sq, P.idx, smem, bid, t);
        else               sel_stage<2>(P.Dp, P.sq, P.idx, smem, bid, t);
        gbar(P.bar, ++ep);

        // ---------------- agg stage (n split into 2 halves -> Co*4 jobs)
        const int CoLg = (Co == 128) ? 7 : 6;
#pragma unroll 1
        for (int job = bid; job < Co * 4; job += NBLK) {
            int o = job & (Co - 1); int rest = job >> CoLg;
            int b = rest & 1; int h = rest >> 1;
            float* Ash = smem;
            float* red = smem + 1024;
            size_t rowoff = (size_t)(b * Co + o) * NPTS;
            {
                float rA[4];
#pragma unroll
                for (int r = 0; r < 4; ++r) rA[r] = cld(&P.A[rowoff + r * 256 + t]);
#pragma unroll
                for (int r = 0; r < 4; ++r) Ash[r * 256 + t] = rA[r];
            }
            __syncthreads();
            float sum = 0.f, sumsq = 0.f;
#pragma unroll 1
            for (int r = 0; r < 2; ++r) {
                int n = h * 512 + r * 256 + t;
                const int* ip = P.idx + (size_t)b * KEFF * NPTS + n;
                float s1 = 0.f, s2 = 0.f, mx = -3.4e38f;
#pragma unroll
                for (int kb = 0; kb < 4; ++kb) {
                    int iv[16];
#pragma unroll
                    for (int m = 0; m < 16; ++m)
                        iv[m] = cldi(&ip[(size_t)(kb * 16 + m) * NPTS]);
                    float av[16];
#pragma unroll
                    for (int m = 0; m < 16; ++m) av[m] = Ash[iv[m]];
#pragma unroll
                    for (int m = 0; m < 16; m += 4) {
                        s1 += av[m] + av[m+1] + av[m+2] + av[m+3];
                        s2 += av[m]*av[m] + av[m+1]*av[m+1] + av[m+2]*av[m+2] + av[m+3]*av[m+3];
                        mx = fmaxf(mx, fmaxf(fmaxf(av[m], av[m+1]), fmaxf(av[m+2], av[m+3])));
                    }
                }
                float bv = cld(&P.Bv[rowoff + n]);
                cst(&P.xconM[((size_t)b * 384 + chOut + o) * NPTS + n], mx + bv);
                sum   += s1 + 64.f * bv;
                sumsq += s2 + 2.f * bv * s1 + 64.f * bv * bv;
            }
            red[t] = sum; __syncthreads();
            for (int s = 128; s > 0; s >>= 1) { if (t < s) red[t] += red[t + s]; __syncthreads(); }
            if (t == 0) cst(&P.part[(size_t)l * 1024 + ((b * Co + o) * 2 + h) * 2 + 0], red[0]);
            __syncthreads();
            red[t] = sumsq; __syncthreads();
            for (int s = 128; s > 0; s >>= 1) { if (t < s) red[t] += red[t + s]; __syncthreads(); }
            if (t == 0) cst(&P.part[(size_t)l * 1024 + ((b * Co + o) * 2 + h) * 2 + 1], red[0]);
            __syncthreads();
        }
        gbar(P.bar, ++ep);
    }

    // ---------------- final GEMM (64o x 32n tiles -> 384 jobs)
    for (int ch = t; ch < 384; ch += 256) {
        const float* pl; const float* gl; const float* bl; int o, Col;
        if (ch < 128)      { pl = P.part;         gl = P.g0; bl = P.be0; o = ch;       Col = 128; }
        else if (ch < 256) { pl = P.part + 1024;  gl = P.g1; bl = P.be1; o = ch - 128; Col = 128; }
        else if (ch < 320) { pl = P.part + 2048;  gl = P.g2; bl = P.be2; o = ch - 256; Col = 64;  }
        else               { pl = P.part + 3072;  gl = P.g3; bl = P.be3; o = ch - 320; Col = 64;  }
        float s  = cld(&pl[4 * o])     + cld(&pl[4 * o + 2])     + cld(&pl[4 * (Col + o)])     + cld(&pl[4 * (Col + o) + 2]);
        float s2 = cld(&pl[4 * o + 1]) + cld(&pl[4 * o + 3])     + cld(&pl[4 * (Col + o) + 1]) + cld(&pl[4 * (Col + o) + 3]);
        const float invc = 1.f / 131072.f;
        float mu = s * invc;
        float var = s2 * invc - mu * mu;
        float rs = rsqrtf(var + 1e-5f);
        float sc = gl[o] * rs;
        shsc[ch] = sc;
        shsh[ch] = bl[o] - mu * sc;
    }
    __syncthreads();
    const float* wlT = P.wt + 122880;
#pragma unroll 1
    for (int job = bid; job < 384; job += NBLK) {
        int nt = job & 31; int rest = job >> 5;
        int ot = rest % 6; int b = rest / 6;
        int n0 = nt * 32, o0 = ot * 64;
        int tn2 = (t & 15) * 2, to4 = (t >> 4) * 4;
        int nn = t & 31, cx0 = t >> 5;
        int woo = t & 63, cw0 = t >> 6;
        float* Xs = smem;
        float* Wl = smem + 1024;
        float2 acc2[4];
#pragma unroll
        for (int i = 0; i < 4; ++i) acc2[i] = make_float2(0.f, 0.f);
        for (int c0 = 0; c0 < 384; c0 += 32) {
            float rx[4], rw[8];
#pragma unroll
            for (int k = 0; k < 4; ++k)
                rx[k] = cld(&P.xconM[((size_t)b * 384 + c0 + cx0 + k * 8) * NPTS + n0 + nn]);
#pragma unroll
            for (int k = 0; k < 8; ++k)
                rw[k] = wlT[(size_t)(c0 + cw0 + k * 4) * 384 + o0 + woo];
#pragma unroll
            for (int k = 0; k < 4; ++k) {
                int cc = c0 + cx0 + k * 8;
                float y = fmaf(rx[k], shsc[cc], shsh[cc]);
                rx[k] = y >= 0.f ? y : 0.2f * y;
            }
            __syncthreads();
#pragma unroll
            for (int k = 0; k < 4; ++k)
                Xs[(cx0 + k * 8) * 32 + nn] = rx[k];
#pragma unroll
            for (int k = 0; k < 8; ++k)
                Wl[(cw0 + k * 4) * 68 + woo] = rw[k];
            __syncthreads();
#pragma unroll 8
            for (int cc = 0; cc < 32; ++cc) {
                float2 xv = *(const float2*)&Xs[cc * 32 + tn2];
                float4 wv = *(const float4*)&Wl[cc * 68 + to4];
                float wvv[4] = {wv.x, wv.y, wv.z, wv.w};
#pragma unroll
                for (int i = 0; i < 4; ++i) {
                    acc2[i].x = fmaf(wvv[i], xv.x, acc2[i].x);
                    acc2[i].y = fmaf(wvv[i], xv.y, acc2[i].y);
                }
            }
        }
#pragma unroll
        for (int i = 0; i < 4; ++i)
            *(float2*)&P.out[((size_t)b * 384 + o0 + to4 + i) * NPTS + n0 + tn2] = acc2[i];
        __syncthreads();
    }
}

extern "C" void kernel_launch(void* const* d_in, const int* in_sizes, int n_in,
                              void* d_out, int out_size, void* d_ws, size_t ws_size,
                              hipStream_t stream) {
    const float* x  = (const float*)d_in[0];
    const float* w[4]  = {(const float*)d_in[1], (const float*)d_in[4], (const float*)d_in[7], (const float*)d_in[10]};
    const float* g[4]  = {(const float*)d_in[2], (const float*)d_in[5], (const float*)d_in[8], (const float*)d_in[11]};
    const float* be[4] = {(const float*)d_in[3], (const float*)d_in[6], (const float*)d_in[9], (const float*)d_in[12]};
    const float* wl = (const float*)d_in[13];

    float* ws    = (float*)d_ws;
    float* xconM = ws;                       // 786432
    float* A     = xconM + 786432;           // 262144
    float* Bv    = A + 262144;               // 262144
    float* sq    = Bv + 262144;              // 2048
    float* Dp    = sq + 2048;                // 8 planes * 458752 = 3670016
    float* part  = Dp + 3670016;             // 4096 (4 layers x 1024)
    float* wt    = part + 4096;              // 270336
    int*   idx   = (int*)(wt + 270336);      // 131072 ints (k-major: [b][k][n])
    unsigned* bar = (unsigned*)(idx + 131072);  // (NBLK+1)*BAR_STRIDE uints

    kprep<<<204, 256, 0, stream>>>(w[0], w[1], w[2], w[3], wl, wt, bar);

    MP mp;
    mp.x = x;
    mp.g0 = g[0]; mp.g1 = g[1]; mp.g2 = g[2]; mp.g3 = g[3];
    mp.be0 = be[0]; mp.be1 = be[1]; mp.be2 = be[2]; mp.be3 = be[3];
    mp.xconM = xconM; mp.A = A; mp.Bv = Bv; mp.sq = sq; mp.Dp = Dp;
    mp.part = part; mp.wt = wt; mp.idx = idx; mp.bar = bar;
    mp.out = (float*)d_out;
    kmega<<<NBLK, 256, 0, stream>>>(mp);
}

// Round 7
// 326.326 us; speedup vs baseline: 4.9721x; 1.0261x over previous
//
#include <hip/hip_runtime.h>
#include <math.h>

#define NPTS 1024
#define CAND 224   // 7*32
#define KEFF 64
#define BATCH 2
#define NEGV -1e30f
#define PLANE (BATCH * NPTS * CAND)
#define NBLK 512
#define BAR_STRIDE 16   // 64B per arrival flag (no false sharing)

// R7 = R6 with VERSIONED cross-stage buffers + cached reads.
// R6 post-mortem: bound by uncached-path traffic (244MB @ ~950GB/s ~= dur). Biggest
// term: read amplification (idx re-read by every agg o-job ~190MB logical; sq scatter;
// xconM 7x window overlap) because ALL cross-stage reads bypassed L1/L2.
// Fix: stale-cache hazard only exists for cached-read-then-REWRITTEN addresses within
// one launch (kernel boundaries flush/inv caches). So: sc1-write-ONCE buffers are safe
// to read with normal cached loads (first read pulls from LLC). xconM/part already
// write-once; idx/sq now versioned per layer (+1.6MB ws). A/Bv/Dp stay address-reused
// -> keep uncached (cld) reads; their traffic is small/unamplified.

#define AG __HIP_MEMORY_SCOPE_AGENT
__device__ __forceinline__ float cld(const float* p) {
    return __hip_atomic_load((float*)p, __ATOMIC_RELAXED, AG);
}
__device__ __forceinline__ void cst(float* p, float v) {
    __hip_atomic_store(p, v, __ATOMIC_RELAXED, AG);
}
__device__ __forceinline__ void csti(int* p, int v) {
    __hip_atomic_store(p, v, __ATOMIC_RELAXED, AG);
}
__device__ __forceinline__ void cst2(float* p, float2 v) {
    union { float2 f; unsigned long long u; } c; c.f = v;
    __hip_atomic_store((unsigned long long*)p, c.u, __ATOMIC_RELAXED, AG);
}

// ================================================================ weight prep (+ barrier init)
__global__ __launch_bounds__(256) void kprep(const float* __restrict__ w0, const float* __restrict__ w1,
                                             const float* __restrict__ w2, const float* __restrict__ w3,
                                             const float* __restrict__ wl, float* __restrict__ wt,
                                             unsigned* __restrict__ bar) {
    __shared__ float tA[32][33];
    __shared__ float tB[32][33];
    int id = blockIdx.x;
    int t = threadIdx.x;
    // zero the whole barrier region every launch (arrival flags + release flag)
    for (int i = id * 256 + t; i < NBLK * BAR_STRIDE + BAR_STRIDE; i += 204 * 256)
        bar[i] = 0u;
    int row = t >> 5, col = t & 31;
    const float* W = w0; int Cin = 256, Co = 128; float* WtA = wt; float* WtB = wt + 32768;
    int tc = 0, to = 0; bool isWL = false;
    if (id < 32)      { int r = id;      tc = r >> 2; to = r & 3; }
    else if (id < 48) { W = w1; Cin = 128; Co = 128; WtA = wt + 65536;  WtB = wt + 81920;  int r = id - 32; tc = r >> 2; to = r & 3; }
    else if (id < 56) { W = w2; Cin = 128; Co = 64;  WtA = wt + 98304;  WtB = wt + 106496; int r = id - 48; tc = r >> 1; to = r & 1; }
    else if (id < 60) { W = w3; Cin = 64;  Co = 64;  WtA = wt + 114688; WtB = wt + 118784; int r = id - 56; tc = r >> 1; to = r & 1; }
    else { isWL = true; int r = id - 60; tc = r / 12; to = r % 12; }
    if (!isWL) {
#pragma unroll
        for (int r = 0; r < 4; ++r) {
            int o = to * 32 + row + r * 8;
            int c = tc * 32 + col;
            float va = W[(size_t)o * 2 * Cin + c];
            tA[row + r * 8][col] = va;
            tB[row + r * 8][col] = W[(size_t)o * 2 * Cin + Cin + c] - va;
        }
        __syncthreads();
#pragma unroll
        for (int r = 0; r < 4; ++r) {
            int c = tc * 32 + row + r * 8;
            int o = to * 32 + col;
            WtA[(size_t)c * Co + o] = tA[col][row + r * 8];
            WtB[(size_t)c * Co + o] = tB[col][row + r * 8];
        }
    } else {
        float* wlT = wt + 122880;
#pragma unroll
        for (int r = 0; r < 4; ++r) {
            int o = to * 32 + row + r * 8;
            int c = tc * 32 + col;
            tA[row + r * 8][col] = wl[(size_t)o * 384 + c];
        }
        __syncthreads();
#pragma unroll
        for (int r = 0; r < 4; ++r) {
            int c = tc * 32 + row + r * 8;
            int o = to * 32 + col;
            wlT[(size_t)c * 384 + o] = tA[col][row + r * 8];
        }
    }
}

// ================================================================ grid barrier (fence-free: coherent flags only)
__device__ __forceinline__ void gbar(unsigned* bar, unsigned ep) {
    __syncthreads();   // hw-drains vmcnt(0): all sc1 data stores ack'd at the coherent point
    const int t = threadIdx.x;
    const int bid = blockIdx.x;
    unsigned* rel = bar + (size_t)NBLK * BAR_STRIDE;
    if (bid == 0) {
        if (t == 0)
            __hip_atomic_store(&bar[0], ep, __ATOMIC_RELAXED, AG);
        for (int s = t; s < NBLK; s += 256) {
            while (__hip_atomic_load(&bar[(size_t)s * BAR_STRIDE], __ATOMIC_RELAXED, AG) < ep)
                __builtin_amdgcn_s_sleep(1);
        }
        __syncthreads();
        if (t == 0)
            __hip_atomic_store(rel, ep, __ATOMIC_RELAXED, AG);
    } else {
        if (t == 0) {
            __hip_atomic_store(&bar[(size_t)bid * BAR_STRIDE], ep, __ATOMIC_RELAXED, AG);
            while (__hip_atomic_load(rel, __ATOMIC_RELAXED, AG) < ep)
                __builtin_amdgcn_s_sleep(1);
        }
    }
    __syncthreads();
}

// ================================================================ select stage (per layer; sq cached, Dp uncached)
template<int NCH>
__device__ __forceinline__ void sel_stage(const float* __restrict__ Dp, const float* __restrict__ sq,
                                          int* __restrict__ idxo, float* smem, int bid, int t) {
    unsigned long long* Dsh = (unsigned long long*)smem;
    int wv = t >> 6, ln = t & 63;
#pragma unroll 1
    for (int job = bid; job < 512; job += NBLK) {
        int b = job >> 8;
        int n = (job & 255) * 4 + wv;
        int i = n >> 5;
        float sqn = sq[b * NPTS + n];
        float pr[4][NCH];
        float sqw[4];
#pragma unroll
        for (int j = 0; j < 4; ++j) {
            int w = ln + 64 * j;
            if (w < CAND) {
                size_t off = ((size_t)b * NPTS + n) * CAND + w;
#pragma unroll
                for (int ch = 0; ch < NCH; ++ch)
                    pr[j][ch] = cld(&Dp[off + (size_t)ch * PLANE]);
                int wb = i - 3 + (w >> 5);
                int wbc = wb < 0 ? 0 : (wb > 31 ? 31 : wb);
                sqw[j] = sq[b * NPTS + wbc * 32 + (w & 31)];
            }
        }
        unsigned long long kj[4];
#pragma unroll
        for (int j = 0; j < 4; ++j) {
            int w = ln + 64 * j;
            if (w < CAND) {
                float s = 0.f;
#pragma unroll
                for (int ch = 0; ch < NCH; ++ch) s += pr[j][ch];
                int wb = i - 3 + (w >> 5);
                bool valid = (wb >= 0) && (wb < 32);
                float d = 2.f * s - sqn - sqw[j];
                d = valid ? d : NEGV;
                unsigned u = __float_as_uint(d);
                u ^= ((unsigned)((int)u >> 31)) | 0x80000000u;
                unsigned long long key = ((unsigned long long)u << 8) | (unsigned long long)(255 - w);
                kj[j] = key;
                Dsh[wv * 224 + w] = key;
            } else {
                kj[j] = 0ull;
            }
        }
        __syncthreads();
        int cnt[4] = {0, 0, 0, 0};
        const ulonglong2* row = (const ulonglong2*)(Dsh + wv * 224);
#pragma unroll 2
        for (int w2 = 0; w2 < 112; w2 += 4) {
            ulonglong2 k0 = row[w2], k1 = row[w2 + 1], k2 = row[w2 + 2], k3 = row[w2 + 3];
#pragma unroll
            for (int j = 0; j < 4; ++j) {
                unsigned long long kk = kj[j];
                cnt[j] += (int)(k0.x > kk) + (int)(k0.y > kk) + (int)(k1.x > kk) + (int)(k1.y > kk)
                        + (int)(k2.x > kk) + (int)(k2.y > kk) + (int)(k3.x > kk) + (int)(k3.y > kk);
            }
        }
#pragma unroll
        for (int j = 0; j < 4; ++j) {
            int w = ln + 64 * j;
            if (w < CAND && cnt[j] < KEFF)
                csti(&idxo[((size_t)b * KEFF + cnt[j]) * NPTS + n], (i - 3) * 32 + w);   // k-major
        }
        __syncthreads();
    }
}

// ================================================================ the fused persistent kernel
struct MP {
    const float* x;
    const float* g0; const float* g1; const float* g2; const float* g3;
    const float* be0; const float* be1; const float* be2; const float* be3;
    float* xconM; float* A; float* Bv; float* sq; float* Dp; float* part; float* wt;
    int* idx; unsigned* bar; float* out;
};

__global__ __launch_bounds__(256, 3) void kmega(MP P) {
    __shared__ __align__(16) float smem[7168];
    __shared__ float shsc[384];
    __shared__ float shsh[384];
    const int t = threadIdx.x;
    const int bid = blockIdx.x;
    unsigned ep = 0;

#pragma unroll 1
    for (int l = 0; l < 4; ++l) {
        const int Cin   = (l == 0) ? 256 : (l == 3) ? 64 : 128;
        const int Co    = (l < 2) ? 128 : 64;
        const int nch   = (l == 0) ? 8 : (l == 3) ? 2 : 4;
        const int nchLg = (l == 0) ? 3 : (l == 3) ? 1 : 2;
        const int chOut = (l == 0) ? 0 : (l == 1) ? 128 : (l == 2) ? 256 : 320;
        const float* xin = (l == 0) ? P.x : P.xconM + (size_t)(l - 1) * 131072;
        const int bstride = (l == 0) ? 262144 : 393216;
        const float* WtA = P.wt + ((l == 0) ? 0 : (l == 1) ? 65536 : (l == 2) ? 98304 : 114688);
        const float* WtB = P.wt + ((l == 0) ? 32768 : (l == 1) ? 81920 : (l == 2) ? 106496 : 118784);
        float* sql = P.sq + l * 2048;                    // versioned per layer
        int*   idxl = P.idx + (size_t)l * 131072;        // versioned per layer

        // BN scale/shift for this layer's input (prev layer's 4 partials per channel) — cached reads
        if (l > 0 && t < Cin) {
            const float* pp = P.part + (size_t)(l - 1) * 1024;
            const float* gPr = (l == 1) ? P.g0  : (l == 2) ? P.g1  : P.g2;
            const float* bPr = (l == 1) ? P.be0 : (l == 2) ? P.be1 : P.be2;
            float s  = pp[4 * t]     + pp[4 * t + 2]     + pp[4 * (Cin + t)]     + pp[4 * (Cin + t) + 2];
            float s2 = pp[4 * t + 1] + pp[4 * t + 3]     + pp[4 * (Cin + t) + 1] + pp[4 * (Cin + t) + 3];
            const float invc = 1.f / 131072.f;
            float mu = s * invc;
            float var = s2 * invc - mu * mu;
            float rs = rsqrtf(var + 1e-5f);
            float sc = gPr[t] * rs;
            shsc[t] = sc;
            shsh[t] = bPr[t] - mu * sc;
        }
        __syncthreads();

        // ---------------- gemm stage (role A: A/Bv/sq tiles; role B: gram partials)
        const int nOT = Co >> 6;
        const int notLg = nOT - 1;          // 2->1, 1->0
        const int nABx = 32 * nOT * BATCH;
        const int nJobs = nABx + nch * 32 * BATCH;
#pragma unroll 1
        for (int job = bid; job < nJobs; job += NBLK) {
            if (job < nABx) {
                int nt = job & 31; int rest = job >> 5;
                int ot = rest & (nOT - 1); int b = rest >> notLg;
                int tn2 = (t & 15) * 2, to4 = (t >> 4) * 4;
                int n0 = nt * 32, o0 = ot * 64;
                const float* xb = xin + (size_t)b * bstride + n0;
                float* Xs = smem; float* Wta = smem + 1024; float* Wtb = smem + 3200;
                float2 a2[4], b2[4], s2v;
#pragma unroll
                for (int q = 0; q < 4; ++q) { a2[q] = make_float2(0.f, 0.f); b2[q] = make_float2(0.f, 0.f); }
                s2v = make_float2(0.f, 0.f);
                int xcc0 = t >> 5, xnn = t & 31;
                int wcc0 = t >> 6, woo = t & 63;
                for (int c0 = 0; c0 < Cin; c0 += 32) {
                    float rx[4], ra[8], rb[8];
#pragma unroll
                    for (int k = 0; k < 4; ++k)
                        rx[k] = xb[(size_t)(c0 + xcc0 + k * 8) * NPTS + xnn];   // cached (x immutable / xconM write-once)
#pragma unroll
                    for (int k = 0; k < 8; ++k) {
                        ra[k] = WtA[(size_t)(c0 + wcc0 + k * 4) * Co + o0 + woo];
                        rb[k] = WtB[(size_t)(c0 + wcc0 + k * 4) * Co + o0 + woo];
                    }
                    if (l > 0) {
#pragma unroll
                        for (int k = 0; k < 4; ++k) {
                            int cc = xcc0 + k * 8;
                            float y = fmaf(rx[k], shsc[c0 + cc], shsh[c0 + cc]);
                            rx[k] = y >= 0.f ? y : 0.2f * y;
                        }
                    }
                    __syncthreads();
#pragma unroll
                    for (int k = 0; k < 4; ++k)
                        Xs[(xcc0 + k * 8) * 32 + xnn] = rx[k];
#pragma unroll
                    for (int k = 0; k < 8; ++k) {
                        Wta[(wcc0 + k * 4) * 68 + woo] = ra[k];
                        Wtb[(wcc0 + k * 4) * 68 + woo] = rb[k];
                    }
                    __syncthreads();
#pragma unroll 8
                    for (int cc = 0; cc < 32; ++cc) {
                        float2 xv = *(const float2*)&Xs[cc * 32 + tn2];
                        float4 wa = *(const float4*)&Wta[cc * 68 + to4];
                        float4 wb = *(const float4*)&Wtb[cc * 68 + to4];
                        s2v.x = fmaf(xv.x, xv.x, s2v.x);
                        s2v.y = fmaf(xv.y, xv.y, s2v.y);
                        float wav[4] = {wa.x, wa.y, wa.z, wa.w};
                        float wbv[4] = {wb.x, wb.y, wb.z, wb.w};
#pragma unroll
                        for (int q = 0; q < 4; ++q) {
                            a2[q].x = fmaf(wav[q], xv.x, a2[q].x);
                            a2[q].y = fmaf(wav[q], xv.y, a2[q].y);
                            b2[q].x = fmaf(wbv[q], xv.x, b2[q].x);
                            b2[q].y = fmaf(wbv[q], xv.y, b2[q].y);
                        }
                    }
                }
                int n = n0 + tn2;
                if (ot == 0 && to4 == 0)
                    cst2(&sql[b * NPTS + n], s2v);
#pragma unroll
                for (int q = 0; q < 4; ++q) {
                    int o = o0 + to4 + q;
                    size_t off = ((size_t)(b * Co + o)) * NPTS + n;
                    cst2(&P.A[off], a2[q]);
                    cst2(&P.Bv[off], b2[q]);
                }
            } else {
                int id2 = job - nABx;
                int chunk = id2 & (nch - 1); int rest = id2 >> nchLg;
                int i = rest & 31; int b = rest >> 5;
                int c0 = chunk * 32;
                const float* xb = xin + (size_t)b * bstride;
                float* Xc = smem;
                int q = t >> 3;
                int wg = t & 7;
                float r[28];
                int rcc[28], rw[28];
#pragma unroll
                for (int k = 0; k < 28; ++k) {
                    int e = t + k * 256;
                    int cc = e / CAND;
                    int w  = e - cc * CAND;
                    rcc[k] = cc; rw[k] = w;
                    int wb = i - 3 + (w >> 5);
                    wb = wb < 0 ? 0 : (wb > 31 ? 31 : wb);
                    r[k] = xb[(size_t)(c0 + cc) * NPTS + wb * 32 + (w & 31)];   // cached
                }
                if (l > 0) {
#pragma unroll
                    for (int k = 0; k < 28; ++k) {
                        float y = fmaf(r[k], shsc[c0 + rcc[k]], shsh[c0 + rcc[k]]);
                        r[k] = y >= 0.f ? y : 0.2f * y;
                    }
                }
#pragma unroll
                for (int k = 0; k < 28; ++k)
                    Xc[rcc[k] * CAND + rw[k]] = r[k];
                __syncthreads();
                float acc[28];
#pragma unroll
                for (int j = 0; j < 28; ++j) acc[j] = 0.f;
                for (int cc = 0; cc < 32; ++cc) {
                    float qv = Xc[cc * CAND + 96 + q];
                    const float4* rowp = (const float4*)&Xc[cc * CAND + wg * 28];
#pragma unroll
                    for (int j4 = 0; j4 < 7; ++j4) {
                        float4 v = rowp[j4];
                        acc[j4 * 4 + 0] = fmaf(qv, v.x, acc[j4 * 4 + 0]);
                        acc[j4 * 4 + 1] = fmaf(qv, v.y, acc[j4 * 4 + 1]);
                        acc[j4 * 4 + 2] = fmaf(qv, v.z, acc[j4 * 4 + 2]);
                        acc[j4 * 4 + 3] = fmaf(qv, v.w, acc[j4 * 4 + 3]);
                    }
                }
                int n = i * 32 + q;
                size_t base = (((size_t)chunk * BATCH + b) * NPTS + n) * CAND + wg * 28;
                float* op = &P.Dp[base];
#pragma unroll
                for (int j4 = 0; j4 < 7; ++j4) {
                    cst2(op + j4 * 4,     make_float2(acc[j4 * 4],     acc[j4 * 4 + 1]));
                    cst2(op + j4 * 4 + 2, make_float2(acc[j4 * 4 + 2], acc[j4 * 4 + 3]));
                }
            }
            __syncthreads();   // job-end: LDS reuse safe
        }
        gbar(P.bar, ++ep);

        // ---------------- select stage
        if (nch == 8)      sel_stage<8>(P.Dp, sql, idxl, smem, bid, t);
        else if (nch == 4) sel_stage<4>(P.Dp, sql, idxl, smem, bid, t);
        else               sel_stage<2>(P.Dp, sql, idxl, smem, bid, t);
        gbar(P.bar, ++ep);

        // ---------------- agg stage (n split into 2 halves -> Co*4 jobs); idx cached
        const int CoLg = (Co == 128) ? 7 : 6;
#pragma unroll 1
        for (int job = bid; job < Co * 4; job += NBLK) {
            int o = job & (Co - 1); int rest = job >> CoLg;
            int b = rest & 1; int h = rest >> 1;
            float* Ash = smem;
            float* red = smem + 1024;
            size_t rowoff = (size_t)(b * Co + o) * NPTS;
            {
                float rA[4];
#pragma unroll
                for (int r = 0; r < 4; ++r) rA[r] = cld(&P.A[rowoff + r * 256 + t]);
#pragma unroll
                for (int r = 0; r < 4; ++r) Ash[r * 256 + t] = rA[r];
            }
            __syncthreads();
            float sum = 0.f, sumsq = 0.f;
#pragma unroll 1
            for (int r = 0; r < 2; ++r) {
                int n = h * 512 + r * 256 + t;
                const int* ip = idxl + (size_t)b * KEFF * NPTS + n;
                float s1 = 0.f, s2 = 0.f, mx = -3.4e38f;
#pragma unroll
                for (int kb = 0; kb < 4; ++kb) {
                    int iv[16];
#pragma unroll
                    for (int m = 0; m < 16; ++m)
                        iv[m] = ip[(size_t)(kb * 16 + m) * NPTS];   // cached (idx versioned, write-once)
                    float av[16];
#pragma unroll
                    for (int m = 0; m < 16; ++m) av[m] = Ash[iv[m]];
#pragma unroll
                    for (int m = 0; m < 16; m += 4) {
                        s1 += av[m] + av[m+1] + av[m+2] + av[m+3];
                        s2 += av[m]*av[m] + av[m+1]*av[m+1] + av[m+2]*av[m+2] + av[m+3]*av[m+3];
                        mx = fmaxf(mx, fmaxf(fmaxf(av[m], av[m+1]), fmaxf(av[m+2], av[m+3])));
                    }
                }
                float bv = cld(&P.Bv[rowoff + n]);
                cst(&P.xconM[((size_t)b * 384 + chOut + o) * NPTS + n], mx + bv);
                sum   += s1 + 64.f * bv;
                sumsq += s2 + 2.f * bv * s1 + 64.f * bv * bv;
            }
            red[t] = sum; __syncthreads();
            for (int s = 128; s > 0; s >>= 1) { if (t < s) red[t] += red[t + s]; __syncthreads(); }
            if (t == 0) cst(&P.part[(size_t)l * 1024 + ((b * Co + o) * 2 + h) * 2 + 0], red[0]);
            __syncthreads();
            red[t] = sumsq; __syncthreads();
            for (int s = 128; s > 0; s >>= 1) { if (t < s) red[t] += red[t + s]; __syncthreads(); }
            if (t == 0) cst(&P.part[(size_t)l * 1024 + ((b * Co + o) * 2 + h) * 2 + 1], red[0]);
            __syncthreads();
        }
        gbar(P.bar, ++ep);
    }

    // ---------------- final GEMM (64o x 32n tiles -> 384 jobs); all reads cached
    for (int ch = t; ch < 384; ch += 256) {
        const float* pl; const float* gl; const float* bl; int o, Col;
        if (ch < 128)      { pl = P.part;         gl = P.g0; bl = P.be0; o = ch;       Col = 128; }
        else if (ch < 256) { pl = P.part + 1024;  gl = P.g1; bl = P.be1; o = ch - 128; Col = 128; }
        else if (ch < 320) { pl = P.part + 2048;  gl = P.g2; bl = P.be2; o = ch - 256; Col = 64;  }
        else               { pl = P.part + 3072;  gl = P.g3; bl = P.be3; o = ch - 320; Col = 64;  }
        float s  = pl[4 * o]     + pl[4 * o + 2]     + pl[4 * (Col + o)]     + pl[4 * (Col + o) + 2];
        float s2 = pl[4 * o + 1] + pl[4 * o + 3]     + pl[4 * (Col + o) + 1] + pl[4 * (Col + o) + 3];
        const float invc = 1.f / 131072.f;
        float mu = s * invc;
        float var = s2 * invc - mu * mu;
        float rs = rsqrtf(var + 1e-5f);
        float sc = gl[o] * rs;
        shsc[ch] = sc;
        shsh[ch] = bl[o] - mu * sc;
    }
    __syncthreads();
    const float* wlT = P.wt + 122880;
#pragma unroll 1
    for (int job = bid; job < 384; job += NBLK) {
        int nt = job & 31; int rest = job >> 5;
        int ot = rest % 6; int b = rest / 6;
        int n0 = nt * 32, o0 = ot * 64;
        int tn2 = (t & 15) * 2, to4 = (t >> 4) * 4;
        int nn = t & 31, cx0 = t >> 5;
        int woo = t & 63, cw0 = t >> 6;
        float* Xs = smem;
        float* Wl = smem + 1024;
        float2 acc2[4];
#pragma unroll
        for (int i = 0; i < 4; ++i) acc2[i] = make_float2(0.f, 0.f);
        for (int c0 = 0; c0 < 384; c0 += 32) {
            float rx[4], rw[8];
#pragma unroll
            for (int k = 0; k < 4; ++k)
                rx[k] = P.xconM[((size_t)b * 384 + c0 + cx0 + k * 8) * NPTS + n0 + nn];   // cached
#pragma unroll
            for (int k = 0; k < 8; ++k)
                rw[k] = wlT[(size_t)(c0 + cw0 + k * 4) * 384 + o0 + woo];
#pragma unroll
            for (int k = 0; k < 4; ++k) {
                int cc = c0 + cx0 + k * 8;
                float y = fmaf(rx[k], shsc[cc], shsh[cc]);
                rx[k] = y >= 0.f ? y : 0.2f * y;
            }
            __syncthreads();
#pragma unroll
            for (int k = 0; k < 4; ++k)
                Xs[(cx0 + k * 8) * 32 + nn] = rx[k];
#pragma unroll
            for (int k = 0; k < 8; ++k)
                Wl[(cw0 + k * 4) * 68 + woo] = rw[k];
            __syncthreads();
#pragma unroll 8
            for (int cc = 0; cc < 32; ++cc) {
                float2 xv = *(const float2*)&Xs[cc * 32 + tn2];
                float4 wv = *(const float4*)&Wl[cc * 68 + to4];
                float wvv[4] = {wv.x, wv.y, wv.z, wv.w};
#pragma unroll
                for (int i = 0; i < 4; ++i) {
                    acc2[i].x = fmaf(wvv[i], xv.x, acc2[i].x);
                    acc2[i].y = fmaf(wvv[i], xv.y, acc2[i].y);
                }
            }
        }
#pragma unroll
        for (int i = 0; i < 4; ++i)
            *(float2*)&P.out[((size_t)b * 384 + o0 + to4 + i) * NPTS + n0 + tn2] = acc2[i];
        __syncthreads();
    }
}

extern "C" void kernel_launch(void* const* d_in, const int* in_sizes, int n_in,
                              void* d_out, int out_size, void* d_ws, size_t ws_size,
                              hipStream_t stream) {
    const float* x  = (const float*)d_in[0];
    const float* w[4]  = {(const float*)d_in[1], (const float*)d_in[4], (const float*)d_in[7], (const float*)d_in[10]};
    const float* g[4]  = {(const float*)d_in[2], (const float*)d_in[5], (const float*)d_in[8], (const float*)d_in[11]};
    const float* be[4] = {(const float*)d_in[3], (const float*)d_in[6], (const float*)d_in[9], (const float*)d_in[12]};
    const float* wl = (const float*)d_in[13];

    float* ws    = (float*)d_ws;
    float* xconM = ws;                       // 786432
    float* A     = xconM + 786432;           // 262144
    float* Bv    = A + 262144;               // 262144
    float* sq    = Bv + 262144;              // 8192 (4 layers x 2048, versioned)
    float* Dp    = sq + 8192;                // 3670016 (shared across layers, uncached path)
    float* part  = Dp + 3670016;             // 4096 (4 layers x 1024, write-once)
    float* wt    = part + 4096;              // 270336
    int*   idx   = (int*)(wt + 270336);      // 4 x 131072 ints (versioned per layer)
    unsigned* bar = (unsigned*)(idx + 524288);  // (NBLK+1)*BAR_STRIDE uints

    kprep<<<204, 256, 0, stream>>>(w[0], w[1], w[2], w[3], wl, wt, bar);

    MP mp;
    mp.x = x;
    mp.g0 = g[0]; mp.g1 = g[1]; mp.g2 = g[2]; mp.g3 = g[3];
    mp.be0 = be[0]; mp.be1 = be[1]; mp.be2 = be[2]; mp.be3 = be[3];
    mp.xconM = xconM; mp.A = A; mp.Bv = Bv; mp.sq = sq; mp.Dp = Dp;
    mp.part = part; mp.wt = wt; mp.idx = idx; mp.bar = bar;
    mp.out = (float*)d_out;
    kmega<<<NBLK, 256, 0, stream>>>(mp);
}